// Round 2
// baseline (426.189 us; speedup 1.0000x reference)
//
#include <hip/hip_runtime.h>
#include <hip/hip_bf16.h>

typedef __bf16 bf16;
typedef __bf16 bf16x8 __attribute__((ext_vector_type(8)));
typedef float  f32x4  __attribute__((ext_vector_type(4)));

#define B_  4
#define N_  2048
#define D_  1024
#define H_  16
#define HD_ 64

__device__ __forceinline__ bf16x8 ld8(const bf16* p) {
  return *reinterpret_cast<const bf16x8*>(p);
}

// ---------------- f32 -> bf16 cast (8 elems/thread) ----------------------------
__global__ __launch_bounds__(256) void cast_k(const float* __restrict__ in,
                                              bf16* __restrict__ out, int n) {
  int i = (blockIdx.x * 256 + threadIdx.x) * 8;
  if (i >= n) return;
  float4 a = *reinterpret_cast<const float4*>(in + i);
  float4 b = *reinterpret_cast<const float4*>(in + i + 4);
  bf16x8 o;
  o[0] = (bf16)a.x; o[1] = (bf16)a.y; o[2] = (bf16)a.z; o[3] = (bf16)a.w;
  o[4] = (bf16)b.x; o[5] = (bf16)b.y; o[6] = (bf16)b.z; o[7] = (bf16)b.w;
  *reinterpret_cast<bf16x8*>(out + i) = o;
}

// ---------------- transpose-cast 1024x1024: out[c][r] = (bf16)in[r][c] ----------
__global__ __launch_bounds__(1024) void transpose_k(const float* __restrict__ in,
                                                    bf16* __restrict__ out) {
  __shared__ float t[32][33];
  int c = blockIdx.x * 32 + threadIdx.x;
  int r = blockIdx.y * 32 + threadIdx.y;
  t[threadIdx.y][threadIdx.x] = in[r * D_ + c];
  __syncthreads();
  int oc = blockIdx.y * 32 + threadIdx.x;
  int orr = blockIdx.x * 32 + threadIdx.y;
  out[orr * D_ + oc] = (bf16)t[threadIdx.x][threadIdx.y];
}

// ---------------- GEMM: C[M,Nn] = A[M,K] * Bt[Nn,K]^T  (bf16 in, f32 acc) -------
// MODE 0: head-split bf16 out [B,H,N,HD]   (for Q and K)
// MODE 1: transposed-per-head bf16 out [B,H,HD,N]  (for V)
// MODE 2: f32 out row-major [M,Nn] + f32 bias
template<int MODE>
__global__ __launch_bounds__(256)
void gemm_k(const bf16* __restrict__ A, const bf16* __restrict__ Bt,
            void* __restrict__ Cv, const float* __restrict__ bias,
            int M, int Nn, int K)
{
  __shared__ bf16 As[128][40];   // +8 pad keeps 16B alignment, spreads banks
  __shared__ bf16 Bs[128][40];
  const int tid  = threadIdx.x;
  const int lane = tid & 63;
  const int wid  = tid >> 6;
  const int brow = blockIdx.x * 128;
  const int bcol = blockIdx.y * 128;
  const int wr   = (wid >> 1) * 64;
  const int wc   = (wid & 1) * 64;
  const int l15  = lane & 15;
  const int lk   = (lane >> 4) * 8;

  f32x4 acc[4][4] = {};

  for (int kb = 0; kb < K; kb += 32) {
#pragma unroll
    for (int rep = 0; rep < 2; ++rep) {
      int idx = tid + rep * 256;
      int row = idx >> 2;
      int col = (idx & 3) * 8;
      *reinterpret_cast<int4*>(&As[row][col]) =
          *reinterpret_cast<const int4*>(&A[(size_t)(brow + row) * K + kb + col]);
      *reinterpret_cast<int4*>(&Bs[row][col]) =
          *reinterpret_cast<const int4*>(&Bt[(size_t)(bcol + row) * K + kb + col]);
    }
    __syncthreads();

    bf16x8 af[4], bfr[4];
#pragma unroll
    for (int m = 0; m < 4; ++m)
      af[m] = *reinterpret_cast<const bf16x8*>(&As[wr + m * 16 + l15][lk]);
#pragma unroll
    for (int n = 0; n < 4; ++n)
      bfr[n] = *reinterpret_cast<const bf16x8*>(&Bs[wc + n * 16 + l15][lk]);
#pragma unroll
    for (int m = 0; m < 4; ++m)
#pragma unroll
      for (int n = 0; n < 4; ++n)
        acc[m][n] = __builtin_amdgcn_mfma_f32_16x16x32_bf16(af[m], bfr[n], acc[m][n], 0, 0, 0);
    __syncthreads();
  }

  const int r0 = (lane >> 4) * 4;
#pragma unroll
  for (int m = 0; m < 4; ++m)
#pragma unroll
    for (int n = 0; n < 4; ++n)
#pragma unroll
      for (int r = 0; r < 4; ++r) {
        int grow = brow + wr + m * 16 + r0 + r;
        int gcol = bcol + wc + n * 16 + l15;
        float v = acc[m][n][r];
        if (MODE == 0) {
          int b = grow >> 11, nn = grow & (N_ - 1);
          int h = gcol >> 6, hd = gcol & 63;
          ((bf16*)Cv)[((((size_t)(b * H_ + h)) * N_ + nn) << 6) + hd] = (bf16)v;
        } else if (MODE == 1) {
          int b = grow >> 11, nn = grow & (N_ - 1);
          int h = gcol >> 6, hd = gcol & 63;
          ((bf16*)Cv)[((size_t)((b * H_ + h) * HD_ + hd)) * N_ + nn] = (bf16)v;
        } else {
          ((float*)Cv)[(size_t)grow * Nn + gcol] = v + bias[gcol];
        }
      }
}

// ---------------- fused causal flash attention --------------------------------
// q,k: [B,H,N,64] bf16;  vt: [B,H,64,N] bf16;  ctx out (bf16): [B,N,D]
// grid (N/128, B*H), 256 thr; each wave independently owns 32 q-rows.
__global__ __launch_bounds__(256)
void attn_k(const bf16* __restrict__ q, const bf16* __restrict__ k,
            const bf16* __restrict__ vt, bf16* __restrict__ ctx)
{
  __shared__ bf16 P[4][2][16][40];
  const int tid  = threadIdx.x;
  const int lane = tid & 63;
  const int wid  = tid >> 6;
  const int bh   = blockIdx.y;                    // b*H + h
  const int qbase = blockIdx.x * 128 + wid * 32;
  const int l15 = lane & 15;
  const int g   = lane >> 4;
  const int lk  = g * 8;

  const bf16* qp = q  + ((size_t)bh * N_ + qbase) * HD_;
  const bf16* kp = k  + (size_t)bh * N_ * HD_;
  const bf16* vp = vt + (size_t)bh * HD_ * N_;

  bf16x8 aq[2][2];
#pragma unroll
  for (int m = 0; m < 2; ++m)
#pragma unroll
    for (int c = 0; c < 2; ++c)
      aq[m][c] = ld8(qp + (size_t)(m * 16 + l15) * HD_ + c * 32 + lk);

  float m_run[2][4], l_run[2][4];
  f32x4 oacc[2][4] = {};
#pragma unroll
  for (int m = 0; m < 2; ++m)
#pragma unroll
    for (int r = 0; r < 4; ++r) { m_run[m][r] = -1e30f; l_run[m][r] = 0.f; }

  const int kmax = qbase + 31;
  for (int kb = 0; kb <= kmax; kb += 32) {
    bf16x8 bk[2][2];
#pragma unroll
    for (int t = 0; t < 2; ++t)
#pragma unroll
      for (int c = 0; c < 2; ++c)
        bk[t][c] = ld8(kp + (size_t)(kb + t * 16 + l15) * HD_ + c * 32 + lk);

    f32x4 s[2][2] = {};
#pragma unroll
    for (int m = 0; m < 2; ++m)
#pragma unroll
      for (int t = 0; t < 2; ++t) {
        s[m][t] = __builtin_amdgcn_mfma_f32_16x16x32_bf16(aq[m][0], bk[t][0], s[m][t], 0, 0, 0);
        s[m][t] = __builtin_amdgcn_mfma_f32_16x16x32_bf16(aq[m][1], bk[t][1], s[m][t], 0, 0, 0);
      }

    // scale + causal mask (key <= query)
#pragma unroll
    for (int m = 0; m < 2; ++m)
#pragma unroll
      for (int t = 0; t < 2; ++t)
#pragma unroll
        for (int r = 0; r < 4; ++r) {
          int kq = kb + t * 16 + l15;
          int qr = qbase + m * 16 + g * 4 + r;
          float val = s[m][t][r] * 0.125f;
          s[m][t][r] = (kq <= qr) ? val : -1e30f;
        }

#pragma unroll
    for (int m = 0; m < 2; ++m) {
      float pm[4], al[4], rs[4];
#pragma unroll
      for (int r = 0; r < 4; ++r) pm[r] = fmaxf(s[m][0][r], s[m][1][r]);
#pragma unroll
      for (int off = 1; off <= 8; off <<= 1)
#pragma unroll
        for (int r = 0; r < 4; ++r) pm[r] = fmaxf(pm[r], __shfl_xor(pm[r], off));
#pragma unroll
      for (int r = 0; r < 4; ++r) {
        float mn = fmaxf(m_run[m][r], pm[r]);
        al[r] = __expf(m_run[m][r] - mn);
        m_run[m][r] = mn;
      }
#pragma unroll
      for (int t = 0; t < 2; ++t)
#pragma unroll
        for (int r = 0; r < 4; ++r) s[m][t][r] = __expf(s[m][t][r] - m_run[m][r]);
#pragma unroll
      for (int r = 0; r < 4; ++r) rs[r] = s[m][0][r] + s[m][1][r];
#pragma unroll
      for (int off = 1; off <= 8; off <<= 1)
#pragma unroll
        for (int r = 0; r < 4; ++r) rs[r] += __shfl_xor(rs[r], off);
#pragma unroll
      for (int r = 0; r < 4; ++r) l_run[m][r] = l_run[m][r] * al[r] + rs[r];
#pragma unroll
      for (int n = 0; n < 4; ++n)
#pragma unroll
        for (int r = 0; r < 4; ++r) oacc[m][n][r] *= al[r];
#pragma unroll
      for (int t = 0; t < 2; ++t)
#pragma unroll
        for (int r = 0; r < 4; ++r)
          P[wid][m][g * 4 + r][t * 16 + l15] = (bf16)s[m][t][r];
    }

    bf16x8 pa[2];
#pragma unroll
    for (int m = 0; m < 2; ++m)
      pa[m] = *reinterpret_cast<const bf16x8*>(&P[wid][m][l15][lk]);

#pragma unroll
    for (int n = 0; n < 4; ++n) {
      bf16x8 vf = ld8(vp + (size_t)(n * 16 + l15) * N_ + kb + lk);
#pragma unroll
      for (int m = 0; m < 2; ++m)
        oacc[m][n] = __builtin_amdgcn_mfma_f32_16x16x32_bf16(pa[m], vf, oacc[m][n], 0, 0, 0);
    }
  }

  const int b = bh >> 4, h = bh & 15;
  bf16* cp = ctx + ((size_t)b * N_ + qbase) * D_ + h * HD_;
#pragma unroll
  for (int m = 0; m < 2; ++m) {
    float inv[4];
#pragma unroll
    for (int r = 0; r < 4; ++r) inv[r] = 1.f / l_run[m][r];
#pragma unroll
    for (int n = 0; n < 4; ++n)
#pragma unroll
      for (int r = 0; r < 4; ++r)
        cp[(size_t)(m * 16 + g * 4 + r) * D_ + n * 16 + l15] = (bf16)(oacc[m][n][r] * inv[r]);
  }
}

// ---------------- launcher ----------------------------------------------------
extern "C" void kernel_launch(void* const* d_in, const int* in_sizes, int n_in,
                              void* d_out, int out_size, void* d_ws, size_t ws_size,
                              hipStream_t stream)
{
  const float* x  = (const float*)d_in[0];
  const float* Wq = (const float*)d_in[1];
  const float* Wk = (const float*)d_in[2];
  const float* Wv = (const float*)d_in[3];
  const float* Wo = (const float*)d_in[4];
  const float* bo = (const float*)d_in[5];
  float* out = (float*)d_out;

  const size_t SZ_BHND = (size_t)B_ * H_ * N_ * HD_ * sizeof(bf16); // 16 MiB
  const size_t SZ_W    = (size_t)D_ * D_ * sizeof(bf16);            // 2 MiB
  char* ws = (char*)d_ws;
  bf16* xbf = (bf16*)(ws);                    // reused as ctx after QKV gemms
  bf16* ctx = (bf16*)(ws);
  bf16* qb  = (bf16*)(ws + SZ_BHND);
  bf16* kbf = (bf16*)(ws + 2 * SZ_BHND);
  bf16* vtb = (bf16*)(ws + 3 * SZ_BHND);
  bf16* wqt = (bf16*)(ws + 4 * SZ_BHND);
  bf16* wkt = (bf16*)(ws + 4 * SZ_BHND + SZ_W);
  bf16* wvt = (bf16*)(ws + 4 * SZ_BHND + 2 * SZ_W);
  bf16* wob = (bf16*)(ws + 4 * SZ_BHND + 3 * SZ_W);
  if (ws_size < 4 * SZ_BHND + 4 * SZ_W) return;  // fail loudly (output stays 0)

  const int NX = B_ * N_ * D_;      // 8M
  cast_k<<<NX / (256 * 8), 256, 0, stream>>>(x, xbf, NX);
  cast_k<<<(D_ * D_) / (256 * 8), 256, 0, stream>>>(Wo, wob, D_ * D_);

  dim3 tb(32, 32), tg(32, 32);
  transpose_k<<<tg, tb, 0, stream>>>(Wq, wqt);
  transpose_k<<<tg, tb, 0, stream>>>(Wk, wkt);
  transpose_k<<<tg, tb, 0, stream>>>(Wv, wvt);

  const int M = B_ * N_;  // 8192
  dim3 gg(M / 128, D_ / 128);
  gemm_k<0><<<gg, 256, 0, stream>>>(xbf, wqt, qb,  nullptr, M, D_, D_);
  gemm_k<0><<<gg, 256, 0, stream>>>(xbf, wkt, kbf, nullptr, M, D_, D_);
  gemm_k<1><<<gg, 256, 0, stream>>>(xbf, wvt, vtb, nullptr, M, D_, D_);

  attn_k<<<dim3(N_ / 128, B_ * H_), 256, 0, stream>>>(qb, kbf, vtb, ctx);

  gemm_k<2><<<gg, 256, 0, stream>>>(ctx, wob, (void*)out, bo, M, D_, D_);
}

// Round 3
// 295.563 us; speedup vs baseline: 1.4420x; 1.4420x over previous
//
#include <hip/hip_runtime.h>
#include <hip/hip_bf16.h>

typedef __bf16 bf16;
typedef __bf16 bf16x8 __attribute__((ext_vector_type(8)));
typedef float  f32x4  __attribute__((ext_vector_type(4)));

#define B_  4
#define N_  2048
#define D_  1024
#define H_  16
#define HD_ 64

// 0.125 (1/sqrt(64)) * log2(e): folds softmax scale + exp->exp2 into Q projection
#define QSCALE 0.1803368801111204f

__device__ __forceinline__ bf16x8 ld8(const bf16* p) {
  return *reinterpret_cast<const bf16x8*>(p);
}

// ---------------- f32 -> bf16 cast (8 elems/thread) ----------------------------
__global__ __launch_bounds__(256) void cast_k(const float* __restrict__ in,
                                              bf16* __restrict__ out, int n) {
  int i = (blockIdx.x * 256 + threadIdx.x) * 8;
  if (i >= n) return;
  float4 a = *reinterpret_cast<const float4*>(in + i);
  float4 b = *reinterpret_cast<const float4*>(in + i + 4);
  bf16x8 o;
  o[0] = (bf16)a.x; o[1] = (bf16)a.y; o[2] = (bf16)a.z; o[3] = (bf16)a.w;
  o[4] = (bf16)b.x; o[5] = (bf16)b.y; o[6] = (bf16)b.z; o[7] = (bf16)b.w;
  *reinterpret_cast<bf16x8*>(out + i) = o;
}

// ---------------- transpose-cast 1024x1024: out[c][r] = (bf16)in[r][c] ----------
__global__ __launch_bounds__(1024) void transpose_k(const float* __restrict__ in,
                                                    bf16* __restrict__ out) {
  __shared__ float t[32][33];
  int c = blockIdx.x * 32 + threadIdx.x;
  int r = blockIdx.y * 32 + threadIdx.y;
  t[threadIdx.y][threadIdx.x] = in[r * D_ + c];
  __syncthreads();
  int oc = blockIdx.y * 32 + threadIdx.x;
  int orr = blockIdx.x * 32 + threadIdx.y;
  out[orr * D_ + oc] = (bf16)t[threadIdx.x][threadIdx.y];
}

// ---------------- GEMM: C[M,Nn] = ascale * A[M,K] * Bt[Nn,K]^T  ----------------
// MODE 0: head-split bf16 out [B,H,N,HD]   (for Q and K)
// MODE 1: transposed-per-head bf16 out [B,H,HD,N]  (for V)
// MODE 2: f32 out row-major [M,Nn] + f32 bias
template<int MODE>
__global__ __launch_bounds__(256)
void gemm_k(const bf16* __restrict__ A, const bf16* __restrict__ Bt,
            void* __restrict__ Cv, const float* __restrict__ bias,
            int M, int Nn, int K, float ascale)
{
  __shared__ bf16 As[128][40];
  __shared__ bf16 Bs[128][40];
  const int tid  = threadIdx.x;
  const int lane = tid & 63;
  const int wid  = tid >> 6;
  const int brow = blockIdx.x * 128;
  const int bcol = blockIdx.y * 128;
  const int wr   = (wid >> 1) * 64;
  const int wc   = (wid & 1) * 64;
  const int l15  = lane & 15;
  const int lk   = (lane >> 4) * 8;

  f32x4 acc[4][4] = {};

  for (int kb = 0; kb < K; kb += 32) {
#pragma unroll
    for (int rep = 0; rep < 2; ++rep) {
      int idx = tid + rep * 256;
      int row = idx >> 2;
      int col = (idx & 3) * 8;
      *reinterpret_cast<int4*>(&As[row][col]) =
          *reinterpret_cast<const int4*>(&A[(size_t)(brow + row) * K + kb + col]);
      *reinterpret_cast<int4*>(&Bs[row][col]) =
          *reinterpret_cast<const int4*>(&Bt[(size_t)(bcol + row) * K + kb + col]);
    }
    __syncthreads();

    bf16x8 af[4], bfr[4];
#pragma unroll
    for (int m = 0; m < 4; ++m)
      af[m] = *reinterpret_cast<const bf16x8*>(&As[wr + m * 16 + l15][lk]);
#pragma unroll
    for (int n = 0; n < 4; ++n)
      bfr[n] = *reinterpret_cast<const bf16x8*>(&Bs[wc + n * 16 + l15][lk]);
#pragma unroll
    for (int m = 0; m < 4; ++m)
#pragma unroll
      for (int n = 0; n < 4; ++n)
        acc[m][n] = __builtin_amdgcn_mfma_f32_16x16x32_bf16(af[m], bfr[n], acc[m][n], 0, 0, 0);
    __syncthreads();
  }

  const int r0 = (lane >> 4) * 4;
#pragma unroll
  for (int m = 0; m < 4; ++m)
#pragma unroll
    for (int n = 0; n < 4; ++n)
#pragma unroll
      for (int r = 0; r < 4; ++r) {
        int grow = brow + wr + m * 16 + r0 + r;
        int gcol = bcol + wc + n * 16 + l15;
        float v = acc[m][n][r] * ascale;
        if (MODE == 0) {
          int b = grow >> 11, nn = grow & (N_ - 1);
          int h = gcol >> 6, hd = gcol & 63;
          ((bf16*)Cv)[((((size_t)(b * H_ + h)) * N_ + nn) << 6) + hd] = (bf16)v;
        } else if (MODE == 1) {
          int b = grow >> 11, nn = grow & (N_ - 1);
          int h = gcol >> 6, hd = gcol & 63;
          ((bf16*)Cv)[((size_t)((b * H_ + h) * HD_ + hd)) * N_ + nn] = (bf16)v;
        } else {
          ((float*)Cv)[(size_t)grow * Nn + gcol] = v + bias[gcol];
        }
      }
}

// ---------------- fused causal flash attention --------------------------------
// q (pre-scaled by QSCALE), k: [B,H,N,64] bf16; vt: [B,H,64,N] bf16
// ctx out (bf16): [B,N,D].  1D grid of 1024 blocks, heavy tiles first (LPT).
__global__ __launch_bounds__(256)
void attn_k(const bf16* __restrict__ q, const bf16* __restrict__ k,
            const bf16* __restrict__ vt, bf16* __restrict__ ctx)
{
  __shared__ bf16 P[4][2][16][72];   // 72-col pad: pa ds_read_b128 is 2-way (free)
  const int tid  = threadIdx.x;
  const int lane = tid & 63;
  const int wid  = tid >> 6;
  const int bid  = blockIdx.x;
  const int bh   = bid & 63;                     // b*H + h
  const int xq   = 15 - (bid >> 6);              // heavy-first
  const int qbase = xq * 128 + wid * 32;
  const int l15 = lane & 15;
  const int g   = lane >> 4;
  const int lk  = g * 8;

  const bf16* qp = q  + ((size_t)bh * N_ + qbase) * HD_;
  const bf16* kp = k  + (size_t)bh * N_ * HD_;
  const bf16* vp = vt + (size_t)bh * HD_ * N_;

  bf16x8 aq[2][2];
#pragma unroll
  for (int m = 0; m < 2; ++m)
#pragma unroll
    for (int c = 0; c < 2; ++c)
      aq[m][c] = ld8(qp + (size_t)(m * 16 + l15) * HD_ + c * 32 + lk);

  float m_run[2][4], l_run[2][4];
  f32x4 oacc[2][4] = {};
#pragma unroll
  for (int m = 0; m < 2; ++m)
#pragma unroll
    for (int r = 0; r < 4; ++r) { m_run[m][r] = -1e30f; l_run[m][r] = 0.f; }

  // ---------- main loop: 64 keys/iter, provably unmasked (kb+63 < qbase) ------
  const int kb_main = qbase & ~63;
  for (int kb = 0; kb < kb_main; kb += 64) {
    bf16x8 bk[4][2];
#pragma unroll
    for (int t = 0; t < 4; ++t)
#pragma unroll
      for (int c = 0; c < 2; ++c)
        bk[t][c] = ld8(kp + (size_t)(kb + t * 16 + l15) * HD_ + c * 32 + lk);

    f32x4 s[2][4] = {};
#pragma unroll
    for (int m = 0; m < 2; ++m)
#pragma unroll
      for (int t = 0; t < 4; ++t) {
        s[m][t] = __builtin_amdgcn_mfma_f32_16x16x32_bf16(aq[m][0], bk[t][0], s[m][t], 0, 0, 0);
        s[m][t] = __builtin_amdgcn_mfma_f32_16x16x32_bf16(aq[m][1], bk[t][1], s[m][t], 0, 0, 0);
      }

#pragma unroll
    for (int m = 0; m < 2; ++m) {
      float pm[4], al[4], rs[4];
#pragma unroll
      for (int r = 0; r < 4; ++r)
        pm[r] = fmaxf(fmaxf(s[m][0][r], s[m][1][r]), fmaxf(s[m][2][r], s[m][3][r]));
#pragma unroll
      for (int off = 1; off <= 8; off <<= 1)
#pragma unroll
        for (int r = 0; r < 4; ++r) pm[r] = fmaxf(pm[r], __shfl_xor(pm[r], off));
#pragma unroll
      for (int r = 0; r < 4; ++r) {
        float mn = fmaxf(m_run[m][r], pm[r]);
        al[r] = exp2f(m_run[m][r] - mn);
        m_run[m][r] = mn;
      }
#pragma unroll
      for (int t = 0; t < 4; ++t)
#pragma unroll
        for (int r = 0; r < 4; ++r) s[m][t][r] = exp2f(s[m][t][r] - m_run[m][r]);
#pragma unroll
      for (int r = 0; r < 4; ++r)
        rs[r] = (s[m][0][r] + s[m][1][r]) + (s[m][2][r] + s[m][3][r]);
#pragma unroll
      for (int off = 1; off <= 8; off <<= 1)
#pragma unroll
        for (int r = 0; r < 4; ++r) rs[r] += __shfl_xor(rs[r], off);
#pragma unroll
      for (int r = 0; r < 4; ++r) l_run[m][r] = l_run[m][r] * al[r] + rs[r];
#pragma unroll
      for (int n = 0; n < 4; ++n)
#pragma unroll
        for (int r = 0; r < 4; ++r) oacc[m][n][r] *= al[r];
#pragma unroll
      for (int t = 0; t < 4; ++t)
#pragma unroll
        for (int r = 0; r < 4; ++r)
          P[wid][m][g * 4 + r][t * 16 + l15] = (bf16)s[m][t][r];
    }

    bf16x8 pa[2][2];
#pragma unroll
    for (int m = 0; m < 2; ++m)
#pragma unroll
      for (int kc = 0; kc < 2; ++kc)
        pa[m][kc] = *reinterpret_cast<const bf16x8*>(&P[wid][m][l15][kc * 32 + lk]);

#pragma unroll
    for (int n = 0; n < 4; ++n)
#pragma unroll
      for (int kc = 0; kc < 2; ++kc) {
        bf16x8 vf = ld8(vp + (size_t)(n * 16 + l15) * N_ + kb + kc * 32 + lk);
#pragma unroll
        for (int m = 0; m < 2; ++m)
          oacc[m][n] = __builtin_amdgcn_mfma_f32_16x16x32_bf16(pa[m][kc], vf, oacc[m][n], 0, 0, 0);
      }
  }

  // ---------- masked tail: 32 keys/iter, kb_main..qbase ------------------------
  for (int kb = kb_main; kb <= qbase; kb += 32) {
    bf16x8 bk[2][2];
#pragma unroll
    for (int t = 0; t < 2; ++t)
#pragma unroll
      for (int c = 0; c < 2; ++c)
        bk[t][c] = ld8(kp + (size_t)(kb + t * 16 + l15) * HD_ + c * 32 + lk);

    f32x4 s[2][2] = {};
#pragma unroll
    for (int m = 0; m < 2; ++m)
#pragma unroll
      for (int t = 0; t < 2; ++t) {
        s[m][t] = __builtin_amdgcn_mfma_f32_16x16x32_bf16(aq[m][0], bk[t][0], s[m][t], 0, 0, 0);
        s[m][t] = __builtin_amdgcn_mfma_f32_16x16x32_bf16(aq[m][1], bk[t][1], s[m][t], 0, 0, 0);
      }

#pragma unroll
    for (int m = 0; m < 2; ++m)
#pragma unroll
      for (int t = 0; t < 2; ++t)
#pragma unroll
        for (int r = 0; r < 4; ++r) {
          int kq = kb + t * 16 + l15;
          int qr = qbase + m * 16 + g * 4 + r;
          if (kq > qr) s[m][t][r] = -1e30f;
        }

#pragma unroll
    for (int m = 0; m < 2; ++m) {
      float pm[4], al[4], rs[4];
#pragma unroll
      for (int r = 0; r < 4; ++r) pm[r] = fmaxf(s[m][0][r], s[m][1][r]);
#pragma unroll
      for (int off = 1; off <= 8; off <<= 1)
#pragma unroll
        for (int r = 0; r < 4; ++r) pm[r] = fmaxf(pm[r], __shfl_xor(pm[r], off));
#pragma unroll
      for (int r = 0; r < 4; ++r) {
        float mn = fmaxf(m_run[m][r], pm[r]);
        al[r] = exp2f(m_run[m][r] - mn);
        m_run[m][r] = mn;
      }
#pragma unroll
      for (int t = 0; t < 2; ++t)
#pragma unroll
        for (int r = 0; r < 4; ++r) s[m][t][r] = exp2f(s[m][t][r] - m_run[m][r]);
#pragma unroll
      for (int r = 0; r < 4; ++r) rs[r] = s[m][0][r] + s[m][1][r];
#pragma unroll
      for (int off = 1; off <= 8; off <<= 1)
#pragma unroll
        for (int r = 0; r < 4; ++r) rs[r] += __shfl_xor(rs[r], off);
#pragma unroll
      for (int r = 0; r < 4; ++r) l_run[m][r] = l_run[m][r] * al[r] + rs[r];
#pragma unroll
      for (int n = 0; n < 4; ++n)
#pragma unroll
        for (int r = 0; r < 4; ++r) oacc[m][n][r] *= al[r];
#pragma unroll
      for (int t = 0; t < 2; ++t)
#pragma unroll
        for (int r = 0; r < 4; ++r)
          P[wid][m][g * 4 + r][t * 16 + l15] = (bf16)s[m][t][r];
    }

    bf16x8 pa[2];
#pragma unroll
    for (int m = 0; m < 2; ++m)
      pa[m] = *reinterpret_cast<const bf16x8*>(&P[wid][m][l15][lk]);

#pragma unroll
    for (int n = 0; n < 4; ++n) {
      bf16x8 vf = ld8(vp + (size_t)(n * 16 + l15) * N_ + kb + lk);
#pragma unroll
      for (int m = 0; m < 2; ++m)
        oacc[m][n] = __builtin_amdgcn_mfma_f32_16x16x32_bf16(pa[m], vf, oacc[m][n], 0, 0, 0);
    }
  }

  const int b = bh >> 4, h = bh & 15;
  bf16* cp = ctx + ((size_t)b * N_ + qbase) * D_ + h * HD_;
#pragma unroll
  for (int m = 0; m < 2; ++m) {
    float inv[4];
#pragma unroll
    for (int r = 0; r < 4; ++r) inv[r] = 1.f / l_run[m][r];
#pragma unroll
    for (int n = 0; n < 4; ++n)
#pragma unroll
      for (int r = 0; r < 4; ++r)
        cp[(size_t)(m * 16 + g * 4 + r) * D_ + n * 16 + l15] = (bf16)(oacc[m][n][r] * inv[r]);
  }
}

// ---------------- launcher ----------------------------------------------------
extern "C" void kernel_launch(void* const* d_in, const int* in_sizes, int n_in,
                              void* d_out, int out_size, void* d_ws, size_t ws_size,
                              hipStream_t stream)
{
  const float* x  = (const float*)d_in[0];
  const float* Wq = (const float*)d_in[1];
  const float* Wk = (const float*)d_in[2];
  const float* Wv = (const float*)d_in[3];
  const float* Wo = (const float*)d_in[4];
  const float* bo = (const float*)d_in[5];
  float* out = (float*)d_out;

  const size_t SZ_BHND = (size_t)B_ * H_ * N_ * HD_ * sizeof(bf16); // 16 MiB
  const size_t SZ_W    = (size_t)D_ * D_ * sizeof(bf16);            // 2 MiB
  char* ws = (char*)d_ws;
  bf16* xbf = (bf16*)(ws);                    // reused as ctx after QKV gemms
  bf16* ctx = (bf16*)(ws);
  bf16* qb  = (bf16*)(ws + SZ_BHND);
  bf16* kbf = (bf16*)(ws + 2 * SZ_BHND);
  bf16* vtb = (bf16*)(ws + 3 * SZ_BHND);
  bf16* wqt = (bf16*)(ws + 4 * SZ_BHND);
  bf16* wkt = (bf16*)(ws + 4 * SZ_BHND + SZ_W);
  bf16* wvt = (bf16*)(ws + 4 * SZ_BHND + 2 * SZ_W);
  bf16* wob = (bf16*)(ws + 4 * SZ_BHND + 3 * SZ_W);
  if (ws_size < 4 * SZ_BHND + 4 * SZ_W) return;

  const int NX = B_ * N_ * D_;      // 8M
  cast_k<<<NX / (256 * 8), 256, 0, stream>>>(x, xbf, NX);
  cast_k<<<(D_ * D_) / (256 * 8), 256, 0, stream>>>(Wo, wob, D_ * D_);

  dim3 tb(32, 32), tg(32, 32);
  transpose_k<<<tg, tb, 0, stream>>>(Wq, wqt);
  transpose_k<<<tg, tb, 0, stream>>>(Wk, wkt);
  transpose_k<<<tg, tb, 0, stream>>>(Wv, wvt);

  const int M = B_ * N_;  // 8192
  dim3 gg(M / 128, D_ / 128);
  gemm_k<0><<<gg, 256, 0, stream>>>(xbf, wqt, qb,  nullptr, M, D_, D_, QSCALE);
  gemm_k<0><<<gg, 256, 0, stream>>>(xbf, wkt, kbf, nullptr, M, D_, D_, 1.0f);
  gemm_k<1><<<gg, 256, 0, stream>>>(xbf, wvt, vtb, nullptr, M, D_, D_, 1.0f);

  attn_k<<<1024, 256, 0, stream>>>(qb, kbf, vtb, ctx);

  gemm_k<2><<<gg, 256, 0, stream>>>(ctx, wob, (void*)out, bo, M, D_, D_, 1.0f);
}

// Round 4
// 262.115 us; speedup vs baseline: 1.6260x; 1.1276x over previous
//
#include <hip/hip_runtime.h>
#include <hip/hip_bf16.h>

typedef __bf16 bf16;
typedef __bf16 bf16x4 __attribute__((ext_vector_type(4)));
typedef __bf16 bf16x8 __attribute__((ext_vector_type(8)));
typedef float  f32x4  __attribute__((ext_vector_type(4)));

#define B_  4
#define N_  2048
#define D_  1024
#define H_  16
#define HD_ 64

// 0.125 (1/sqrt(64)) * log2(e): folded into Wq during transpose
#define QSCALE 0.1803368801111204f

__device__ __forceinline__ bf16x8 ld8(const bf16* p) {
  return *reinterpret_cast<const bf16x8*>(p);
}

// ---------------- f32 -> bf16 cast (8 elems/thread) ----------------------------
__global__ __launch_bounds__(256) void cast_k(const float* __restrict__ in,
                                              bf16* __restrict__ out, int n) {
  int i = (blockIdx.x * 256 + threadIdx.x) * 8;
  if (i >= n) return;
  float4 a = *reinterpret_cast<const float4*>(in + i);
  float4 b = *reinterpret_cast<const float4*>(in + i + 4);
  bf16x8 o;
  o[0] = (bf16)a.x; o[1] = (bf16)a.y; o[2] = (bf16)a.z; o[3] = (bf16)a.w;
  o[4] = (bf16)b.x; o[5] = (bf16)b.y; o[6] = (bf16)b.z; o[7] = (bf16)b.w;
  *reinterpret_cast<bf16x8*>(out + i) = o;
}

// ------- transpose-cast 1024x1024: out[c][r] = (bf16)(scale * in[r][c]) --------
__global__ __launch_bounds__(1024) void transpose_k(const float* __restrict__ in,
                                                    bf16* __restrict__ out, float scale) {
  __shared__ float t[32][33];
  int c = blockIdx.x * 32 + threadIdx.x;
  int r = blockIdx.y * 32 + threadIdx.y;
  t[threadIdx.y][threadIdx.x] = in[r * D_ + c];
  __syncthreads();
  int oc = blockIdx.y * 32 + threadIdx.x;
  int orr = blockIdx.x * 32 + threadIdx.y;
  out[orr * D_ + oc] = (bf16)(scale * t[threadIdx.x][threadIdx.y]);
}

// ---------------- fused QKV GEMM: [8192,1024] x [3072,1024]^T ------------------
// Bt rows 0..1023 = Wq^T (pre-scaled), 1024..2047 = Wk^T, 2048..3071 = Wv^T
// Q,K out: [B,H,N,64] bf16;  V out: [B,H,64,N] bf16
__global__ __launch_bounds__(256)
void gemm_qkv(const bf16* __restrict__ A, const bf16* __restrict__ Bt,
              bf16* __restrict__ qb, bf16* __restrict__ kb, bf16* __restrict__ vtb)
{
  __shared__ bf16 As[128][40];
  __shared__ bf16 Bs[128][40];
  const int tid  = threadIdx.x;
  const int lane = tid & 63;
  const int wid  = tid >> 6;
  const int brow = blockIdx.x * 128;
  const int bcol = blockIdx.y * 128;
  const int wr   = (wid >> 1) * 64;
  const int wc   = (wid & 1) * 64;
  const int l15  = lane & 15;
  const int lk   = (lane >> 4) * 8;
  const int K    = D_;

  f32x4 acc[4][4] = {};

  for (int kk = 0; kk < K; kk += 32) {
#pragma unroll
    for (int rep = 0; rep < 2; ++rep) {
      int idx = tid + rep * 256;
      int row = idx >> 2;
      int col = (idx & 3) * 8;
      *reinterpret_cast<int4*>(&As[row][col]) =
          *reinterpret_cast<const int4*>(&A[(size_t)(brow + row) * K + kk + col]);
      *reinterpret_cast<int4*>(&Bs[row][col]) =
          *reinterpret_cast<const int4*>(&Bt[(size_t)(bcol + row) * K + kk + col]);
    }
    __syncthreads();

    bf16x8 af[4], bfr[4];
#pragma unroll
    for (int m = 0; m < 4; ++m)
      af[m] = *reinterpret_cast<const bf16x8*>(&As[wr + m * 16 + l15][lk]);
#pragma unroll
    for (int n = 0; n < 4; ++n)
      bfr[n] = *reinterpret_cast<const bf16x8*>(&Bs[wc + n * 16 + l15][lk]);
#pragma unroll
    for (int m = 0; m < 4; ++m)
#pragma unroll
      for (int n = 0; n < 4; ++n)
        acc[m][n] = __builtin_amdgcn_mfma_f32_16x16x32_bf16(af[m], bfr[n], acc[m][n], 0, 0, 0);
    __syncthreads();
  }

  // which matrix is block-uniform (128-col blocks never cross the 1024 boundary)
  const int which = bcol >> 10;
  bf16* outp = (which == 0) ? qb : (which == 1) ? kb : vtb;
  const int r0 = (lane >> 4) * 4;
#pragma unroll
  for (int m = 0; m < 4; ++m)
#pragma unroll
    for (int n = 0; n < 4; ++n)
#pragma unroll
      for (int r = 0; r < 4; ++r) {
        int grow = brow + wr + m * 16 + r0 + r;
        int gcol = (bcol & 1023) + wc + n * 16 + l15;
        int b = grow >> 11, nn = grow & (N_ - 1);
        int h = gcol >> 6, hd = gcol & 63;
        float v = acc[m][n][r];
        if (which == 2)
          outp[((size_t)((b * H_ + h) * HD_ + hd)) * N_ + nn] = (bf16)v;
        else
          outp[((((size_t)(b * H_ + h)) * N_ + nn) << 6) + hd] = (bf16)v;
      }
}

// ---------------- output GEMM: out[M,D] = ctx[M,D] x Wo[D,D]^T + bo ------------
__global__ __launch_bounds__(256)
void gemm_out(const bf16* __restrict__ A, const bf16* __restrict__ Bt,
              float* __restrict__ C, const float* __restrict__ bias)
{
  __shared__ bf16 As[128][40];
  __shared__ bf16 Bs[128][40];
  const int tid  = threadIdx.x;
  const int lane = tid & 63;
  const int wid  = tid >> 6;
  const int brow = blockIdx.x * 128;
  const int bcol = blockIdx.y * 128;
  const int wr   = (wid >> 1) * 64;
  const int wc   = (wid & 1) * 64;
  const int l15  = lane & 15;
  const int lk   = (lane >> 4) * 8;
  const int K    = D_;

  f32x4 acc[4][4] = {};

  for (int kk = 0; kk < K; kk += 32) {
#pragma unroll
    for (int rep = 0; rep < 2; ++rep) {
      int idx = tid + rep * 256;
      int row = idx >> 2;
      int col = (idx & 3) * 8;
      *reinterpret_cast<int4*>(&As[row][col]) =
          *reinterpret_cast<const int4*>(&A[(size_t)(brow + row) * K + kk + col]);
      *reinterpret_cast<int4*>(&Bs[row][col]) =
          *reinterpret_cast<const int4*>(&Bt[(size_t)(bcol + row) * K + kk + col]);
    }
    __syncthreads();

    bf16x8 af[4], bfr[4];
#pragma unroll
    for (int m = 0; m < 4; ++m)
      af[m] = *reinterpret_cast<const bf16x8*>(&As[wr + m * 16 + l15][lk]);
#pragma unroll
    for (int n = 0; n < 4; ++n)
      bfr[n] = *reinterpret_cast<const bf16x8*>(&Bs[wc + n * 16 + l15][lk]);
#pragma unroll
    for (int m = 0; m < 4; ++m)
#pragma unroll
      for (int n = 0; n < 4; ++n)
        acc[m][n] = __builtin_amdgcn_mfma_f32_16x16x32_bf16(af[m], bfr[n], acc[m][n], 0, 0, 0);
    __syncthreads();
  }

  const int r0 = (lane >> 4) * 4;
#pragma unroll
  for (int m = 0; m < 4; ++m)
#pragma unroll
    for (int n = 0; n < 4; ++n)
#pragma unroll
      for (int r = 0; r < 4; ++r) {
        int grow = brow + wr + m * 16 + r0 + r;
        int gcol = bcol + wc + n * 16 + l15;
        C[(size_t)grow * D_ + gcol] = acc[m][n][r] + bias[gcol];
      }
}

// ---------------- fused causal flash attention (swapped QK^T) ------------------
// q (pre-scaled), k: [B,H,N,64] bf16; vt: [B,H,64,N] bf16; ctx out bf16 [B,N,D]
// S^T = K·Q^T per tile: lane holds 16 key-scores for ONE query (= lane&15).
__global__ __launch_bounds__(256)
void attn_k(const bf16* __restrict__ q, const bf16* __restrict__ k,
            const bf16* __restrict__ vt, bf16* __restrict__ ctx)
{
  __shared__ bf16 Pl[4][2][16][72];   // [wid][m q-tile][q=16][64 keys + 8 pad]
  const int tid  = threadIdx.x;
  const int lane = tid & 63;
  const int wid  = tid >> 6;
  const int bid  = blockIdx.x;
  const int bh   = bid & 63;                     // b*H + h
  const int xq   = 15 - (bid >> 6);              // heavy-first (LPT)
  const int qbase = xq * 128 + wid * 32;
  const int l15 = lane & 15;
  const int g   = lane >> 4;
  const int lk  = g * 8;

  const bf16* qp = q  + ((size_t)bh * N_ + qbase) * HD_;
  const bf16* kp = k  + (size_t)bh * N_ * HD_;
  const bf16* vp = vt + (size_t)bh * HD_ * N_;

  // Q as B-fragment: B[col=query=l15][k=d chunks]
  bf16x8 aq[2][2];
#pragma unroll
  for (int m = 0; m < 2; ++m)
#pragma unroll
    for (int c = 0; c < 2; ++c)
      aq[m][c] = ld8(qp + (size_t)(m * 16 + l15) * HD_ + c * 32 + lk);

  float m_run[2] = {-1e30f, -1e30f};
  float l_run[2] = {0.f, 0.f};
  f32x4 oacc[4][2] = {};   // O^T: [d-tile n][q-tile m], row=d local, col=q=l15

  const int kb_main = qbase & ~63;

  // K as A-fragment: A[row=key][k=d] — preload first 64-key tile
  bf16x8 bk[4][2];
  if (kb_main > 0) {
#pragma unroll
    for (int t = 0; t < 4; ++t)
#pragma unroll
      for (int c = 0; c < 2; ++c)
        bk[t][c] = ld8(kp + (size_t)(t * 16 + l15) * HD_ + c * 32 + lk);
  }

  // ---------- main loop: 64 keys/iter, provably unmasked ----------------------
  for (int kb = 0; kb < kb_main; kb += 64) {
    f32x4 s[2][4] = {};   // S^T tiles: [q-tile m][key-tile t], row=key, col=q
#pragma unroll
    for (int m = 0; m < 2; ++m)
#pragma unroll
      for (int t = 0; t < 4; ++t) {
        s[m][t] = __builtin_amdgcn_mfma_f32_16x16x32_bf16(bk[t][0], aq[m][0], s[m][t], 0, 0, 0);
        s[m][t] = __builtin_amdgcn_mfma_f32_16x16x32_bf16(bk[t][1], aq[m][1], s[m][t], 0, 0, 0);
      }

    // prefetch next K tile (rows <= kb_main+63 <= 2047: always in-bounds)
#pragma unroll
    for (int t = 0; t < 4; ++t)
#pragma unroll
      for (int c = 0; c < 2; ++c)
        bk[t][c] = ld8(kp + (size_t)(kb + 64 + t * 16 + l15) * HD_ + c * 32 + lk);

    // online softmax, fully in-register key reduction
#pragma unroll
    for (int m = 0; m < 2; ++m) {
      float pm = s[m][0][0];
#pragma unroll
      for (int t = 0; t < 4; ++t)
#pragma unroll
        for (int r = 0; r < 4; ++r) pm = fmaxf(pm, s[m][t][r]);
      pm = fmaxf(pm, __shfl_xor(pm, 16));
      pm = fmaxf(pm, __shfl_xor(pm, 32));
      float mn = fmaxf(m_run[m], pm);
      float al = exp2f(m_run[m] - mn);
      m_run[m] = mn;
      float rs = 0.f;
#pragma unroll
      for (int t = 0; t < 4; ++t)
#pragma unroll
        for (int r = 0; r < 4; ++r) {
          s[m][t][r] = exp2f(s[m][t][r] - mn);
          rs += s[m][t][r];
        }
      rs += __shfl_xor(rs, 16);
      rs += __shfl_xor(rs, 32);
      l_run[m] = l_run[m] * al + rs;
#pragma unroll
      for (int n = 0; n < 4; ++n)
#pragma unroll
        for (int r = 0; r < 4; ++r) oacc[n][m][r] *= al;
      // P[q][key] -> LDS (packed 4 keys = 8B per store)
#pragma unroll
      for (int t = 0; t < 4; ++t) {
        bf16x4 pk;
#pragma unroll
        for (int r = 0; r < 4; ++r) pk[r] = (bf16)s[m][t][r];
        *reinterpret_cast<bf16x4*>(&Pl[wid][m][l15][t * 16 + g * 4]) = pk;
      }
    }

    // V as A-fragment: A[row=d][k=key], rows n*16+l15, keys kb+kc*32+g*8
    bf16x8 vf[4][2];
#pragma unroll
    for (int n = 0; n < 4; ++n)
#pragma unroll
      for (int kc = 0; kc < 2; ++kc)
        vf[n][kc] = ld8(vp + (size_t)(n * 16 + l15) * N_ + kb + kc * 32 + lk);

    // P as B-fragment: B[col=q=l15][k=key chunks]
    bf16x8 pb[2][2];
#pragma unroll
    for (int m = 0; m < 2; ++m)
#pragma unroll
      for (int kc = 0; kc < 2; ++kc)
        pb[m][kc] = *reinterpret_cast<const bf16x8*>(&Pl[wid][m][l15][kc * 32 + lk]);

#pragma unroll
    for (int n = 0; n < 4; ++n)
#pragma unroll
      for (int kc = 0; kc < 2; ++kc)
#pragma unroll
        for (int m = 0; m < 2; ++m)
          oacc[n][m] = __builtin_amdgcn_mfma_f32_16x16x32_bf16(vf[n][kc], pb[m][kc], oacc[n][m], 0, 0, 0);
  }

  // ---------- masked tail: 32 keys/iter ----------------------------------------
  for (int kb = kb_main; kb <= qbase; kb += 32) {
    bf16x8 bt2[2][2];
#pragma unroll
    for (int t = 0; t < 2; ++t)
#pragma unroll
      for (int c = 0; c < 2; ++c)
        bt2[t][c] = ld8(kp + (size_t)(kb + t * 16 + l15) * HD_ + c * 32 + lk);

    f32x4 s[2][2] = {};
#pragma unroll
    for (int m = 0; m < 2; ++m)
#pragma unroll
      for (int t = 0; t < 2; ++t) {
        s[m][t] = __builtin_amdgcn_mfma_f32_16x16x32_bf16(bt2[t][0], aq[m][0], s[m][t], 0, 0, 0);
        s[m][t] = __builtin_amdgcn_mfma_f32_16x16x32_bf16(bt2[t][1], aq[m][1], s[m][t], 0, 0, 0);
      }

    // causal mask: key = kb + t*16 + g*4 + r, query = qbase + m*16 + l15
#pragma unroll
    for (int m = 0; m < 2; ++m) {
      int qr = qbase + m * 16 + l15;
#pragma unroll
      for (int t = 0; t < 2; ++t)
#pragma unroll
        for (int r = 0; r < 4; ++r) {
          int kq = kb + t * 16 + g * 4 + r;
          if (kq > qr) s[m][t][r] = -1e30f;
        }
    }

#pragma unroll
    for (int m = 0; m < 2; ++m) {
      float pm = s[m][0][0];
#pragma unroll
      for (int t = 0; t < 2; ++t)
#pragma unroll
        for (int r = 0; r < 4; ++r) pm = fmaxf(pm, s[m][t][r]);
      pm = fmaxf(pm, __shfl_xor(pm, 16));
      pm = fmaxf(pm, __shfl_xor(pm, 32));
      float mn = fmaxf(m_run[m], pm);
      float al = exp2f(m_run[m] - mn);
      m_run[m] = mn;
      float rs = 0.f;
#pragma unroll
      for (int t = 0; t < 2; ++t)
#pragma unroll
        for (int r = 0; r < 4; ++r) {
          s[m][t][r] = exp2f(s[m][t][r] - mn);
          rs += s[m][t][r];
        }
      rs += __shfl_xor(rs, 16);
      rs += __shfl_xor(rs, 32);
      l_run[m] = l_run[m] * al + rs;
#pragma unroll
      for (int n = 0; n < 4; ++n)
#pragma unroll
        for (int r = 0; r < 4; ++r) oacc[n][m][r] *= al;
#pragma unroll
      for (int t = 0; t < 2; ++t) {
        bf16x4 pk;
#pragma unroll
        for (int r = 0; r < 4; ++r) pk[r] = (bf16)s[m][t][r];
        *reinterpret_cast<bf16x4*>(&Pl[wid][m][l15][t * 16 + g * 4]) = pk;
      }
    }

    bf16x8 vf[4];
#pragma unroll
    for (int n = 0; n < 4; ++n)
      vf[n] = ld8(vp + (size_t)(n * 16 + l15) * N_ + kb + lk);

    bf16x8 pb[2];
#pragma unroll
    for (int m = 0; m < 2; ++m)
      pb[m] = *reinterpret_cast<const bf16x8*>(&Pl[wid][m][l15][lk]);

#pragma unroll
    for (int n = 0; n < 4; ++n)
#pragma unroll
      for (int m = 0; m < 2; ++m)
        oacc[n][m] = __builtin_amdgcn_mfma_f32_16x16x32_bf16(vf[n], pb[m], oacc[n][m], 0, 0, 0);
  }

  // epilogue: O^T -> ctx[B,N,D]; lane owns query l15, d = n*16 + g*4 + r
  const int b = bh >> 4, h = bh & 15;
#pragma unroll
  for (int m = 0; m < 2; ++m) {
    float inv = 1.f / l_run[m];
    bf16* cp = ctx + ((size_t)b * N_ + qbase + m * 16 + l15) * D_ + h * HD_;
#pragma unroll
    for (int n = 0; n < 4; ++n) {
      bf16x4 o;
#pragma unroll
      for (int r = 0; r < 4; ++r) o[r] = (bf16)(oacc[n][m][r] * inv);
      *reinterpret_cast<bf16x4*>(cp + n * 16 + g * 4) = o;
    }
  }
}

// ---------------- launcher ----------------------------------------------------
extern "C" void kernel_launch(void* const* d_in, const int* in_sizes, int n_in,
                              void* d_out, int out_size, void* d_ws, size_t ws_size,
                              hipStream_t stream)
{
  const float* x  = (const float*)d_in[0];
  const float* Wq = (const float*)d_in[1];
  const float* Wk = (const float*)d_in[2];
  const float* Wv = (const float*)d_in[3];
  const float* Wo = (const float*)d_in[4];
  const float* bo = (const float*)d_in[5];
  float* out = (float*)d_out;

  const size_t SZ_BHND = (size_t)B_ * H_ * N_ * HD_ * sizeof(bf16); // 16 MiB
  const size_t SZ_W    = (size_t)D_ * D_ * sizeof(bf16);            // 2 MiB
  char* ws = (char*)d_ws;
  bf16* xbf  = (bf16*)(ws);                    // reused as ctx after QKV gemm
  bf16* ctx  = (bf16*)(ws);
  bf16* qb   = (bf16*)(ws + SZ_BHND);
  bf16* kbf  = (bf16*)(ws + 2 * SZ_BHND);
  bf16* vtb  = (bf16*)(ws + 3 * SZ_BHND);
  bf16* wqkv = (bf16*)(ws + 4 * SZ_BHND);      // [3072][1024]
  bf16* wob  = (bf16*)(ws + 4 * SZ_BHND + 3 * SZ_W);
  if (ws_size < 4 * SZ_BHND + 4 * SZ_W) return;

  const int NX = B_ * N_ * D_;      // 8M
  cast_k<<<NX / (256 * 8), 256, 0, stream>>>(x, xbf, NX);
  cast_k<<<(D_ * D_) / (256 * 8), 256, 0, stream>>>(Wo, wob, D_ * D_);

  dim3 tb(32, 32), tg(32, 32);
  transpose_k<<<tg, tb, 0, stream>>>(Wq, wqkv, QSCALE);
  transpose_k<<<tg, tb, 0, stream>>>(Wk, wqkv + (size_t)D_ * D_, 1.0f);
  transpose_k<<<tg, tb, 0, stream>>>(Wv, wqkv + 2 * (size_t)D_ * D_, 1.0f);

  const int M = B_ * N_;  // 8192
  gemm_qkv<<<dim3(M / 128, 3 * D_ / 128), 256, 0, stream>>>(xbf, wqkv, qb, kbf, vtb);

  attn_k<<<1024, 256, 0, stream>>>(qb, kbf, vtb, ctx);

  gemm_out<<<dim3(M / 128, D_ / 128), 256, 0, stream>>>(ctx, wob, out, bo);
}

// Round 5
// 251.582 us; speedup vs baseline: 1.6940x; 1.0419x over previous
//
#include <hip/hip_runtime.h>
#include <hip/hip_bf16.h>

typedef __bf16 bf16;
typedef __bf16 bf16x4 __attribute__((ext_vector_type(4)));
typedef __bf16 bf16x8 __attribute__((ext_vector_type(8)));
typedef float  f32x4  __attribute__((ext_vector_type(4)));

#define B_  4
#define N_  2048
#define D_  1024
#define H_  16
#define HD_ 64

// 0.125 (1/sqrt(64)) * log2(e): folded into Wq during transpose
#define QSCALE 0.1803368801111204f

__device__ __forceinline__ bf16x8 ld8(const bf16* p) {
  return *reinterpret_cast<const bf16x8*>(p);
}

// async global->LDS, 16B per lane; lds base must be wave-uniform
__device__ __forceinline__ void gload16(const bf16* g, bf16* l) {
  __builtin_amdgcn_global_load_lds(
      (const __attribute__((address_space(1))) void*)g,
      (__attribute__((address_space(3))) void*)l, 16, 0, 0);
}

// ---------------- f32 -> bf16 cast (8 elems/thread) ----------------------------
__global__ __launch_bounds__(256) void cast_k(const float* __restrict__ in,
                                              bf16* __restrict__ out, int n) {
  int i = (blockIdx.x * 256 + threadIdx.x) * 8;
  if (i >= n) return;
  float4 a = *reinterpret_cast<const float4*>(in + i);
  float4 b = *reinterpret_cast<const float4*>(in + i + 4);
  bf16x8 o;
  o[0] = (bf16)a.x; o[1] = (bf16)a.y; o[2] = (bf16)a.z; o[3] = (bf16)a.w;
  o[4] = (bf16)b.x; o[5] = (bf16)b.y; o[6] = (bf16)b.z; o[7] = (bf16)b.w;
  *reinterpret_cast<bf16x8*>(out + i) = o;
}

// ---- fused transpose-cast of Wq/Wk/Wv (z selects): out[z][c][r] = s*in[z][r][c]
__global__ __launch_bounds__(1024)
void transpose3_k(const float* __restrict__ w0, const float* __restrict__ w1,
                  const float* __restrict__ w2, bf16* __restrict__ out) {
  __shared__ float t[32][33];
  const int z = blockIdx.z;
  const float* in = (z == 0) ? w0 : (z == 1) ? w1 : w2;
  const float scale = (z == 0) ? QSCALE : 1.0f;
  bf16* o = out + (size_t)z * D_ * D_;
  int c = blockIdx.x * 32 + threadIdx.x;
  int r = blockIdx.y * 32 + threadIdx.y;
  t[threadIdx.y][threadIdx.x] = in[r * D_ + c];
  __syncthreads();
  int oc = blockIdx.y * 32 + threadIdx.x;
  int orr = blockIdx.x * 32 + threadIdx.y;
  o[orr * D_ + oc] = (bf16)(scale * t[threadIdx.x][threadIdx.y]);
}

// ---- shared GEMM core: stage 128x32 A/B tiles via global_load_lds, 16 MFMA ----
// As/Bs are linear [128*32] (64 B rows) — required by global_load_lds.
#define GEMM_CORE(A_, Bt_, K_)                                                   \
  f32x4 acc[4][4] = {};                                                          \
  for (int kk = 0; kk < (K_); kk += 32) {                                        \
    _Pragma("unroll")                                                            \
    for (int j = 0; j < 2; ++j) {                                                \
      gload16(&(A_)[(size_t)(brow + wid * 32 + j * 16 + (lane >> 2)) * (K_) +    \
                    kk + (lane & 3) * 8],                                        \
              &As[(wid * 32 + j * 16) * 32]);                                    \
      gload16(&(Bt_)[(size_t)(bcol + wid * 32 + j * 16 + (lane >> 2)) * (K_) +   \
                     kk + (lane & 3) * 8],                                       \
              &Bs[(wid * 32 + j * 16) * 32]);                                    \
    }                                                                            \
    __syncthreads();                                                             \
    bf16x8 af[4], bfr[4];                                                        \
    _Pragma("unroll")                                                            \
    for (int m = 0; m < 4; ++m)                                                  \
      af[m] = *reinterpret_cast<const bf16x8*>(&As[(wr + m * 16 + l15) * 32 + lk]); \
    _Pragma("unroll")                                                            \
    for (int n = 0; n < 4; ++n)                                                  \
      bfr[n] = *reinterpret_cast<const bf16x8*>(&Bs[(wc + n * 16 + l15) * 32 + lk]); \
    _Pragma("unroll")                                                            \
    for (int m = 0; m < 4; ++m)                                                  \
      _Pragma("unroll")                                                          \
      for (int n = 0; n < 4; ++n)                                                \
        acc[m][n] = __builtin_amdgcn_mfma_f32_16x16x32_bf16(af[m], bfr[n],       \
                                                            acc[m][n], 0, 0, 0); \
    __syncthreads();                                                             \
  }

// ---------------- fused QKV GEMM: [8192,1024] x [3072,1024]^T ------------------
__global__ __launch_bounds__(256)
void gemm_qkv(const bf16* __restrict__ A, const bf16* __restrict__ Bt,
              bf16* __restrict__ qb, bf16* __restrict__ kb, bf16* __restrict__ vtb)
{
  __shared__ bf16 As[128 * 32];
  __shared__ bf16 Bs[128 * 32];
  const int tid  = threadIdx.x;
  const int lane = tid & 63;
  const int wid  = tid >> 6;
  const int brow = blockIdx.x * 128;
  const int bcol = blockIdx.y * 128;
  const int wr   = (wid >> 1) * 64;
  const int wc   = (wid & 1) * 64;
  const int l15  = lane & 15;
  const int lk   = (lane >> 4) * 8;

  GEMM_CORE(A, Bt, D_)

  const int which = bcol >> 10;   // 0:Q 1:K 2:V (block-uniform)
  bf16* outp = (which == 0) ? qb : (which == 1) ? kb : vtb;
  const int r0 = (lane >> 4) * 4;
#pragma unroll
  for (int m = 0; m < 4; ++m)
#pragma unroll
    for (int n = 0; n < 4; ++n)
#pragma unroll
      for (int r = 0; r < 4; ++r) {
        int grow = brow + wr + m * 16 + r0 + r;
        int gcol = (bcol & 1023) + wc + n * 16 + l15;
        int b = grow >> 11, nn = grow & (N_ - 1);
        int h = gcol >> 6, hd = gcol & 63;
        float v = acc[m][n][r];
        if (which == 2)
          outp[((size_t)((b * H_ + h) * HD_ + hd)) * N_ + nn] = (bf16)v;
        else
          outp[((((size_t)(b * H_ + h)) * N_ + nn) << 6) + hd] = (bf16)v;
      }
}

// ---------------- output GEMM: out[M,D] = ctx[M,D] x Wo[D,D]^T + bo ------------
__global__ __launch_bounds__(256)
void gemm_out(const bf16* __restrict__ A, const bf16* __restrict__ Bt,
              float* __restrict__ C, const float* __restrict__ bias)
{
  __shared__ bf16 As[128 * 32];
  __shared__ bf16 Bs[128 * 32];
  const int tid  = threadIdx.x;
  const int lane = tid & 63;
  const int wid  = tid >> 6;
  const int brow = blockIdx.x * 128;
  const int bcol = blockIdx.y * 128;
  const int wr   = (wid >> 1) * 64;
  const int wc   = (wid & 1) * 64;
  const int l15  = lane & 15;
  const int lk   = (lane >> 4) * 8;

  GEMM_CORE(A, Bt, D_)

  const int r0 = (lane >> 4) * 4;
#pragma unroll
  for (int m = 0; m < 4; ++m)
#pragma unroll
    for (int n = 0; n < 4; ++n)
#pragma unroll
      for (int r = 0; r < 4; ++r) {
        int grow = brow + wr + m * 16 + r0 + r;
        int gcol = bcol + wc + n * 16 + l15;
        C[(size_t)grow * D_ + gcol] = acc[m][n][r] + bias[gcol];
      }
}

// ---------------- fused causal flash attention (swapped QK^T) ------------------
// 1-wave (64-thread) blocks; 4096 blocks, heavy-first (LPT).
// q (pre-scaled), k: [B,H,N,64] bf16; vt: [B,H,64,N] bf16; ctx out bf16 [B,N,D]
__global__ __launch_bounds__(64)
void attn_k(const bf16* __restrict__ q, const bf16* __restrict__ k,
            const bf16* __restrict__ vt, bf16* __restrict__ ctx)
{
  __shared__ bf16 Pl[2][16][72];
  const int lane = threadIdx.x;
  const int bid  = blockIdx.x;
  const int bh   = bid & 63;                     // b*H + h
  const int qc   = 63 - (bid >> 6);              // heavy-first
  const int qbase = qc * 32;
  const int l15 = lane & 15;
  const int g   = lane >> 4;
  const int lk  = g * 8;

  const bf16* qp = q  + ((size_t)bh * N_ + qbase) * HD_;
  const bf16* kp = k  + (size_t)bh * N_ * HD_;
  const bf16* vp = vt + (size_t)bh * HD_ * N_;

  // Q as B-fragment: B[col=query=l15][k=d chunks]
  bf16x8 aq[2][2];
#pragma unroll
  for (int m = 0; m < 2; ++m)
#pragma unroll
    for (int c = 0; c < 2; ++c)
      aq[m][c] = ld8(qp + (size_t)(m * 16 + l15) * HD_ + c * 32 + lk);

  float m_run[2] = {-1e30f, -1e30f};
  float l_run[2] = {0.f, 0.f};
  f32x4 oacc[4][2] = {};   // O^T: [d-tile n][q-tile m], row=d local, col=q=l15

  const int kb_main = qbase & ~63;

  // K as A-fragment: A[row=key][k=d] — preload first 64-key tile
  bf16x8 bk[4][2];
  if (kb_main > 0) {
#pragma unroll
    for (int t = 0; t < 4; ++t)
#pragma unroll
      for (int c = 0; c < 2; ++c)
        bk[t][c] = ld8(kp + (size_t)(t * 16 + l15) * HD_ + c * 32 + lk);
  }

  // ---------- main loop: 64 keys/iter, provably unmasked ----------------------
  for (int kb = 0; kb < kb_main; kb += 64) {
    f32x4 s[2][4] = {};   // S^T tiles: [q-tile m][key-tile t], row=key, col=q
#pragma unroll
    for (int m = 0; m < 2; ++m)
#pragma unroll
      for (int t = 0; t < 4; ++t) {
        s[m][t] = __builtin_amdgcn_mfma_f32_16x16x32_bf16(bk[t][0], aq[m][0], s[m][t], 0, 0, 0);
        s[m][t] = __builtin_amdgcn_mfma_f32_16x16x32_bf16(bk[t][1], aq[m][1], s[m][t], 0, 0, 0);
      }

    // issue V loads early: latency hides under softmax (T14-lite)
    bf16x8 vf[4][2];
#pragma unroll
    for (int n = 0; n < 4; ++n)
#pragma unroll
      for (int kc = 0; kc < 2; ++kc)
        vf[n][kc] = ld8(vp + (size_t)(n * 16 + l15) * N_ + kb + kc * 32 + lk);

    // prefetch next K tile (max row kb_main+63 <= 2047)
#pragma unroll
    for (int t = 0; t < 4; ++t)
#pragma unroll
      for (int c = 0; c < 2; ++c)
        bk[t][c] = ld8(kp + (size_t)(kb + 64 + t * 16 + l15) * HD_ + c * 32 + lk);

    // online softmax with defer-max (THR=8 in log2 domain)
#pragma unroll
    for (int m = 0; m < 2; ++m) {
      float pm = s[m][0][0];
#pragma unroll
      for (int t = 0; t < 4; ++t)
#pragma unroll
        for (int r = 0; r < 4; ++r) pm = fmaxf(pm, s[m][t][r]);
      pm = fmaxf(pm, __shfl_xor(pm, 16));
      pm = fmaxf(pm, __shfl_xor(pm, 32));
      if (!__all(pm <= m_run[m] + 8.f)) {
        float mn = fmaxf(m_run[m], pm);
        float al = exp2f(m_run[m] - mn);
        m_run[m] = mn;
        l_run[m] *= al;
#pragma unroll
        for (int n = 0; n < 4; ++n)
#pragma unroll
          for (int r = 0; r < 4; ++r) oacc[n][m][r] *= al;
      }
      float rs = 0.f;
#pragma unroll
      for (int t = 0; t < 4; ++t)
#pragma unroll
        for (int r = 0; r < 4; ++r) {
          s[m][t][r] = exp2f(s[m][t][r] - m_run[m]);
          rs += s[m][t][r];
        }
      rs += __shfl_xor(rs, 16);
      rs += __shfl_xor(rs, 32);
      l_run[m] += rs;
      // P[q][key] -> LDS (packed 4 keys = 8B per store)
#pragma unroll
      for (int t = 0; t < 4; ++t) {
        bf16x4 pk;
#pragma unroll
        for (int r = 0; r < 4; ++r) pk[r] = (bf16)s[m][t][r];
        *reinterpret_cast<bf16x4*>(&Pl[m][l15][t * 16 + g * 4]) = pk;
      }
    }

    // P as B-fragment: B[col=q=l15][k=key chunks]
#pragma unroll
    for (int kc = 0; kc < 2; ++kc) {
      bf16x8 pb[2];
#pragma unroll
      for (int m = 0; m < 2; ++m)
        pb[m] = *reinterpret_cast<const bf16x8*>(&Pl[m][l15][kc * 32 + lk]);
#pragma unroll
      for (int n = 0; n < 4; ++n)
#pragma unroll
        for (int m = 0; m < 2; ++m)
          oacc[n][m] = __builtin_amdgcn_mfma_f32_16x16x32_bf16(vf[n][kc], pb[m], oacc[n][m], 0, 0, 0);
    }
  }

  // ---------- masked tail: 32 keys/iter ----------------------------------------
  for (int kb = kb_main; kb <= qbase; kb += 32) {
    bf16x8 bt2[2][2];
#pragma unroll
    for (int t = 0; t < 2; ++t)
#pragma unroll
      for (int c = 0; c < 2; ++c)
        bt2[t][c] = ld8(kp + (size_t)(kb + t * 16 + l15) * HD_ + c * 32 + lk);

    f32x4 s[2][2] = {};
#pragma unroll
    for (int m = 0; m < 2; ++m)
#pragma unroll
      for (int t = 0; t < 2; ++t) {
        s[m][t] = __builtin_amdgcn_mfma_f32_16x16x32_bf16(bt2[t][0], aq[m][0], s[m][t], 0, 0, 0);
        s[m][t] = __builtin_amdgcn_mfma_f32_16x16x32_bf16(bt2[t][1], aq[m][1], s[m][t], 0, 0, 0);
      }

    bf16x8 vf[4];
#pragma unroll
    for (int n = 0; n < 4; ++n)
      vf[n] = ld8(vp + (size_t)(n * 16 + l15) * N_ + kb + lk);

    // causal mask: key = kb + t*16 + g*4 + r, query = qbase + m*16 + l15
#pragma unroll
    for (int m = 0; m < 2; ++m) {
      int qr = qbase + m * 16 + l15;
#pragma unroll
      for (int t = 0; t < 2; ++t)
#pragma unroll
        for (int r = 0; r < 4; ++r) {
          int kq = kb + t * 16 + g * 4 + r;
          if (kq > qr) s[m][t][r] = -1e30f;
        }
    }

#pragma unroll
    for (int m = 0; m < 2; ++m) {
      float pm = s[m][0][0];
#pragma unroll
      for (int t = 0; t < 2; ++t)
#pragma unroll
        for (int r = 0; r < 4; ++r) pm = fmaxf(pm, s[m][t][r]);
      pm = fmaxf(pm, __shfl_xor(pm, 16));
      pm = fmaxf(pm, __shfl_xor(pm, 32));
      if (!__all(pm <= m_run[m] + 8.f)) {
        float mn = fmaxf(m_run[m], pm);
        float al = exp2f(m_run[m] - mn);
        m_run[m] = mn;
        l_run[m] *= al;
#pragma unroll
        for (int n = 0; n < 4; ++n)
#pragma unroll
          for (int r = 0; r < 4; ++r) oacc[n][m][r] *= al;
      }
      float rs = 0.f;
#pragma unroll
      for (int t = 0; t < 2; ++t)
#pragma unroll
        for (int r = 0; r < 4; ++r) {
          s[m][t][r] = exp2f(s[m][t][r] - m_run[m]);
          rs += s[m][t][r];
        }
      rs += __shfl_xor(rs, 16);
      rs += __shfl_xor(rs, 32);
      l_run[m] += rs;
#pragma unroll
      for (int t = 0; t < 2; ++t) {
        bf16x4 pk;
#pragma unroll
        for (int r = 0; r < 4; ++r) pk[r] = (bf16)s[m][t][r];
        *reinterpret_cast<bf16x4*>(&Pl[m][l15][t * 16 + g * 4]) = pk;
      }
    }

    bf16x8 pb[2];
#pragma unroll
    for (int m = 0; m < 2; ++m)
      pb[m] = *reinterpret_cast<const bf16x8*>(&Pl[m][l15][lk]);

#pragma unroll
    for (int n = 0; n < 4; ++n)
#pragma unroll
      for (int m = 0; m < 2; ++m)
        oacc[n][m] = __builtin_amdgcn_mfma_f32_16x16x32_bf16(vf[n], pb[m], oacc[n][m], 0, 0, 0);
  }

  // epilogue: O^T -> ctx[B,N,D]; lane owns query l15, d = n*16 + g*4 + r
  const int b = bh >> 4, h = bh & 15;
#pragma unroll
  for (int m = 0; m < 2; ++m) {
    float inv = 1.f / l_run[m];
    bf16* cp = ctx + ((size_t)b * N_ + qbase + m * 16 + l15) * D_ + h * HD_;
#pragma unroll
    for (int n = 0; n < 4; ++n) {
      bf16x4 o;
#pragma unroll
      for (int r = 0; r < 4; ++r) o[r] = (bf16)(oacc[n][m][r] * inv);
      *reinterpret_cast<bf16x4*>(cp + n * 16 + g * 4) = o;
    }
  }
}

// ---------------- launcher ----------------------------------------------------
extern "C" void kernel_launch(void* const* d_in, const int* in_sizes, int n_in,
                              void* d_out, int out_size, void* d_ws, size_t ws_size,
                              hipStream_t stream)
{
  const float* x  = (const float*)d_in[0];
  const float* Wq = (const float*)d_in[1];
  const float* Wk = (const float*)d_in[2];
  const float* Wv = (const float*)d_in[3];
  const float* Wo = (const float*)d_in[4];
  const float* bo = (const float*)d_in[5];
  float* out = (float*)d_out;

  const size_t SZ_BHND = (size_t)B_ * H_ * N_ * HD_ * sizeof(bf16); // 16 MiB
  const size_t SZ_W    = (size_t)D_ * D_ * sizeof(bf16);            // 2 MiB
  char* ws = (char*)d_ws;
  bf16* xbf  = (bf16*)(ws);                    // reused as ctx after QKV gemm
  bf16* ctx  = (bf16*)(ws);
  bf16* qb   = (bf16*)(ws + SZ_BHND);
  bf16* kbf  = (bf16*)(ws + 2 * SZ_BHND);
  bf16* vtb  = (bf16*)(ws + 3 * SZ_BHND);
  bf16* wqkv = (bf16*)(ws + 4 * SZ_BHND);      // [3072][1024]
  bf16* wob  = (bf16*)(ws + 4 * SZ_BHND + 3 * SZ_W);
  if (ws_size < 4 * SZ_BHND + 4 * SZ_W) return;

  const int NX = B_ * N_ * D_;      // 8M
  cast_k<<<NX / (256 * 8), 256, 0, stream>>>(x, xbf, NX);
  cast_k<<<(D_ * D_) / (256 * 8), 256, 0, stream>>>(Wo, wob, D_ * D_);

  transpose3_k<<<dim3(32, 32, 3), dim3(32, 32), 0, stream>>>(Wq, Wk, Wv, wqkv);

  const int M = B_ * N_;  // 8192
  gemm_qkv<<<dim3(M / 128, 3 * D_ / 128), 256, 0, stream>>>(xbf, wqkv, qb, kbf, vtb);

  attn_k<<<4096, 64, 0, stream>>>(qb, kbf, vtb, ctx);

  gemm_out<<<dim3(M / 128, D_ / 128), 256, 0, stream>>>(ctx, wob, out, bo);
}

// Round 6
// 199.376 us; speedup vs baseline: 2.1376x; 1.2618x over previous
//
#include <hip/hip_runtime.h>
#include <hip/hip_bf16.h>

typedef __bf16 bf16;
typedef __bf16 bf16x4 __attribute__((ext_vector_type(4)));
typedef __bf16 bf16x8 __attribute__((ext_vector_type(8)));
typedef float  f32x4  __attribute__((ext_vector_type(4)));

#define B_  4
#define N_  2048
#define D_  1024
#define H_  16
#define HD_ 64

// 0.125 (1/sqrt(64)) * log2(e): folded into Wq during transpose
#define QSCALE 0.1803368801111204f

__device__ __forceinline__ bf16x8 ld8(const bf16* p) {
  return *reinterpret_cast<const bf16x8*>(p);
}

// async global->LDS, 16B per lane; lds base must be wave-uniform
__device__ __forceinline__ void gload16(const bf16* g, bf16* l) {
  __builtin_amdgcn_global_load_lds(
      (const __attribute__((address_space(1))) void*)g,
      (__attribute__((address_space(3))) void*)l, 16, 0, 0);
}

// ---------------- f32 -> bf16 cast (8 elems/thread) ----------------------------
__global__ __launch_bounds__(256) void cast_k(const float* __restrict__ in,
                                              bf16* __restrict__ out, int n) {
  int i = (blockIdx.x * 256 + threadIdx.x) * 8;
  if (i >= n) return;
  float4 a = *reinterpret_cast<const float4*>(in + i);
  float4 b = *reinterpret_cast<const float4*>(in + i + 4);
  bf16x8 o;
  o[0] = (bf16)a.x; o[1] = (bf16)a.y; o[2] = (bf16)a.z; o[3] = (bf16)a.w;
  o[4] = (bf16)b.x; o[5] = (bf16)b.y; o[6] = (bf16)b.z; o[7] = (bf16)b.w;
  *reinterpret_cast<bf16x8*>(out + i) = o;
}

// ---- fused transpose-cast of Wq/Wk/Wv (z selects): out[z][c][r] = s*in[z][r][c]
__global__ __launch_bounds__(1024)
void transpose3_k(const float* __restrict__ w0, const float* __restrict__ w1,
                  const float* __restrict__ w2, bf16* __restrict__ out) {
  __shared__ float t[32][33];
  const int z = blockIdx.z;
  const float* in = (z == 0) ? w0 : (z == 1) ? w1 : w2;
  const float scale = (z == 0) ? QSCALE : 1.0f;
  bf16* o = out + (size_t)z * D_ * D_;
  int c = blockIdx.x * 32 + threadIdx.x;
  int r = blockIdx.y * 32 + threadIdx.y;
  t[threadIdx.y][threadIdx.x] = in[r * D_ + c];
  __syncthreads();
  int oc = blockIdx.y * 32 + threadIdx.x;
  int orr = blockIdx.x * 32 + threadIdx.y;
  o[orr * D_ + oc] = (bf16)(scale * t[threadIdx.x][threadIdx.y]);
}

// ---- shared GEMM core: stage 128x32 A/B tiles via global_load_lds, 16 MFMA ----
#define GEMM_CORE(A_, Bt_, K_)                                                   \
  f32x4 acc[4][4] = {};                                                          \
  for (int kk = 0; kk < (K_); kk += 32) {                                        \
    _Pragma("unroll")                                                            \
    for (int j = 0; j < 2; ++j) {                                                \
      gload16(&(A_)[(size_t)(brow + wid * 32 + j * 16 + (lane >> 2)) * (K_) +    \
                    kk + (lane & 3) * 8],                                        \
              &As[(wid * 32 + j * 16) * 32]);                                    \
      gload16(&(Bt_)[(size_t)(bcol + wid * 32 + j * 16 + (lane >> 2)) * (K_) +   \
                     kk + (lane & 3) * 8],                                       \
              &Bs[(wid * 32 + j * 16) * 32]);                                    \
    }                                                                            \
    __syncthreads();                                                             \
    bf16x8 af[4], bfr[4];                                                        \
    _Pragma("unroll")                                                            \
    for (int m = 0; m < 4; ++m)                                                  \
      af[m] = *reinterpret_cast<const bf16x8*>(&As[(wr + m * 16 + l15) * 32 + lk]); \
    _Pragma("unroll")                                                            \
    for (int n = 0; n < 4; ++n)                                                  \
      bfr[n] = *reinterpret_cast<const bf16x8*>(&Bs[(wc + n * 16 + l15) * 32 + lk]); \
    _Pragma("unroll")                                                            \
    for (int m = 0; m < 4; ++m)                                                  \
      _Pragma("unroll")                                                          \
      for (int n = 0; n < 4; ++n)                                                \
        acc[m][n] = __builtin_amdgcn_mfma_f32_16x16x32_bf16(af[m], bfr[n],       \
                                                            acc[m][n], 0, 0, 0); \
    __syncthreads();                                                             \
  }

// ---------------- fused QKV GEMM: [8192,1024] x [3072,1024]^T ------------------
__global__ __launch_bounds__(256)
void gemm_qkv(const bf16* __restrict__ A, const bf16* __restrict__ Bt,
              bf16* __restrict__ qb, bf16* __restrict__ kb, bf16* __restrict__ vtb)
{
  __shared__ bf16 As[128 * 32];
  __shared__ bf16 Bs[128 * 32];
  const int tid  = threadIdx.x;
  const int lane = tid & 63;
  const int wid  = tid >> 6;
  const int brow = blockIdx.x * 128;
  const int bcol = blockIdx.y * 128;
  const int wr   = (wid >> 1) * 64;
  const int wc   = (wid & 1) * 64;
  const int l15  = lane & 15;
  const int lk   = (lane >> 4) * 8;

  GEMM_CORE(A, Bt, D_)

  const int which = bcol >> 10;   // 0:Q 1:K 2:V (block-uniform)
  bf16* outp = (which == 0) ? qb : (which == 1) ? kb : vtb;
  const int r0 = (lane >> 4) * 4;
#pragma unroll
  for (int m = 0; m < 4; ++m)
#pragma unroll
    for (int n = 0; n < 4; ++n)
#pragma unroll
      for (int r = 0; r < 4; ++r) {
        int grow = brow + wr + m * 16 + r0 + r;
        int gcol = (bcol & 1023) + wc + n * 16 + l15;
        int b = grow >> 11, nn = grow & (N_ - 1);
        int h = gcol >> 6, hd = gcol & 63;
        float v = acc[m][n][r];
        if (which == 2)
          outp[((size_t)((b * H_ + h) * HD_ + hd)) * N_ + nn] = (bf16)v;
        else
          outp[((((size_t)(b * H_ + h)) * N_ + nn) << 6) + hd] = (bf16)v;
      }
}

// ---------------- output GEMM: out[M,D] = ctx[M,D] x Wo[D,D]^T + bo ------------
__global__ __launch_bounds__(256)
void gemm_out(const bf16* __restrict__ A, const bf16* __restrict__ Bt,
              float* __restrict__ C, const float* __restrict__ bias)
{
  __shared__ bf16 As[128 * 32];
  __shared__ bf16 Bs[128 * 32];
  const int tid  = threadIdx.x;
  const int lane = tid & 63;
  const int wid  = tid >> 6;
  const int brow = blockIdx.x * 128;
  const int bcol = blockIdx.y * 128;
  const int wr   = (wid >> 1) * 64;
  const int wc   = (wid & 1) * 64;
  const int l15  = lane & 15;
  const int lk   = (lane >> 4) * 8;

  GEMM_CORE(A, Bt, D_)

  const int r0 = (lane >> 4) * 4;
#pragma unroll
  for (int m = 0; m < 4; ++m)
#pragma unroll
    for (int n = 0; n < 4; ++n)
#pragma unroll
      for (int r = 0; r < 4; ++r) {
        int grow = brow + wr + m * 16 + r0 + r;
        int gcol = bcol + wc + n * 16 + l15;
        C[(size_t)grow * D_ + gcol] = acc[m][n][r] + bias[gcol];
      }
}

// ---------------- fused causal flash attention: 8-wave shared-KV blocks --------
// q (pre-scaled), k: [B,H,N,64] bf16; vt: [B,H,64,N] bf16; ctx out bf16 [B,N,D]
// 512 blocks x 512 thr. Block = bh + complementary q-chunk pair {c, 15-c} of 128
// rows each => 34 KV tiles per block, perfectly balanced. K/V tiles staged into
// LDS via global_load_lds (double-buffered, XOR-swizzled source, 1 barrier/tile).
__global__ __launch_bounds__(512, 4)
void attn_k(const bf16* __restrict__ q, const bf16* __restrict__ k,
            const bf16* __restrict__ vt, bf16* __restrict__ ctx)
{
  __shared__ bf16 Ks[2][64 * 64];
  __shared__ bf16 Vs[2][64 * 64];
  __shared__ bf16 Pl[8][16][72];
  const int tid  = threadIdx.x;
  const int lane = tid & 63;
  const int wid  = tid >> 6;
  const int bid  = blockIdx.x;
  const int bh   = bid & 63;
  const int cpr  = bid >> 6;          // 0..7
  const int l15  = lane & 15;
  const int g    = lane >> 4;
  const int lk   = g * 8;
  const int swz  = (l15 & 7) << 4;    // read-side XOR swizzle (bytes)

  const bf16* kp = k  + (size_t)bh * N_ * HD_;
  const bf16* vp = vt + (size_t)bh * HD_ * N_;
  const int b = bh >> 4, h = bh & 15;

  // staging mapping: lane -> 1 row of K (key) and 1 row of V (d); dest linear,
  // source column pre-swizzled so that swizzled reads land on the right data.
  const int srow  = wid * 8 + (lane >> 3);             // 0..63
  const int scoff = ((lane & 7) ^ (srow & 7)) * 8;     // elems (=16B units)
  bf16* kdst[2] = { &Ks[0][wid * 8 * 64], &Ks[1][wid * 8 * 64] };
  bf16* vdst[2] = { &Vs[0][wid * 8 * 64], &Vs[1][wid * 8 * 64] };

#pragma unroll
  for (int p = 0; p < 2; ++p) {
    const int qb0   = (p == 0 ? cpr : 15 - cpr) * 128;
    const int qbase = qb0 + wid * 16;
    const int nt    = qb0 / 64 + 2;          // KV tiles this phase
    const int tm    = qbase >> 6;            // masked tile index for this wave

    // Q rows qbase..qbase+15 (query = l15), d chunks c2*32 + g*8
    const bf16* qp = q + ((size_t)bh * N_ + qbase) * HD_;
    bf16x8 aq[2];
#pragma unroll
    for (int c2 = 0; c2 < 2; ++c2)
      aq[c2] = ld8(qp + (size_t)l15 * HD_ + c2 * 32 + lk);

    float m_run = -1e30f, l_run = 0.f;
    f32x4 oacc[4] = {};

    // prologue: stage tile 0 into buf 0
    gload16(kp + (size_t)srow * HD_ + scoff, kdst[0]);
    gload16(vp + (size_t)srow * N_ + scoff, vdst[0]);
    __syncthreads();

    for (int t = 0; t < nt; ++t) {
      const int cur = t & 1;
      if (t + 1 < nt) {   // issue next-tile stage; drains at end-of-iter barrier
        const int kb = (t + 1) * 64;
        gload16(kp + (size_t)(kb + srow) * HD_ + scoff, kdst[cur ^ 1]);
        gload16(vp + (size_t)srow * N_ + kb + scoff, vdst[cur ^ 1]);
      }
      if (t <= tm) {      // wave-uniform: compute only tiles with unmasked keys
        const char* kb_ = (const char*)&Ks[cur][0];
        const char* vb_ = (const char*)&Vs[cur][0];

        // QK^T (swapped): S^T[key][q], A = K rows, B = Q cols
        f32x4 s[4] = {};
#pragma unroll
        for (int tt = 0; tt < 4; ++tt) {
          bf16x8 bk0 = *reinterpret_cast<const bf16x8*>(
              kb_ + (tt * 16 + l15) * 128 + ((g * 16) ^ swz));
          bf16x8 bk1 = *reinterpret_cast<const bf16x8*>(
              kb_ + (tt * 16 + l15) * 128 + ((64 + g * 16) ^ swz));
          s[tt] = __builtin_amdgcn_mfma_f32_16x16x32_bf16(bk0, aq[0], s[tt], 0, 0, 0);
          s[tt] = __builtin_amdgcn_mfma_f32_16x16x32_bf16(bk1, aq[1], s[tt], 0, 0, 0);
        }

        if (t == tm) {    // causal mask on the diagonal tile
          const int qr = qbase + l15;
#pragma unroll
          for (int tt = 0; tt < 4; ++tt)
#pragma unroll
            for (int r = 0; r < 4; ++r) {
              int kq = t * 64 + tt * 16 + g * 4 + r;
              if (kq > qr) s[tt][r] = -1e30f;
            }
        }

        // online softmax (defer-max THR=8, log2 domain)
        float pm = s[0][0];
#pragma unroll
        for (int tt = 0; tt < 4; ++tt)
#pragma unroll
          for (int r = 0; r < 4; ++r) pm = fmaxf(pm, s[tt][r]);
        pm = fmaxf(pm, __shfl_xor(pm, 16));
        pm = fmaxf(pm, __shfl_xor(pm, 32));
        if (!__all(pm <= m_run + 8.f)) {
          float mn = fmaxf(m_run, pm);
          float al = exp2f(m_run - mn);
          m_run = mn;
          l_run *= al;
#pragma unroll
          for (int n = 0; n < 4; ++n)
#pragma unroll
            for (int r = 0; r < 4; ++r) oacc[n][r] *= al;
        }
        float rs = 0.f;
#pragma unroll
        for (int tt = 0; tt < 4; ++tt)
#pragma unroll
          for (int r = 0; r < 4; ++r) {
            s[tt][r] = exp2f(s[tt][r] - m_run);
            rs += s[tt][r];
          }
        rs += __shfl_xor(rs, 16);
        rs += __shfl_xor(rs, 32);
        l_run += rs;

        // P[q][key] -> per-wave LDS (C-layout -> A-layout transpose)
#pragma unroll
        for (int tt = 0; tt < 4; ++tt) {
          bf16x4 pk;
#pragma unroll
          for (int r = 0; r < 4; ++r) pk[r] = (bf16)s[tt][r];
          *reinterpret_cast<bf16x4*>(&Pl[wid][l15][tt * 16 + g * 4]) = pk;
        }

        // PV: O^T += V^T(LDS) * P, A = V rows (d), B = P cols (q)
#pragma unroll
        for (int kc = 0; kc < 2; ++kc) {
          bf16x8 pb = *reinterpret_cast<const bf16x8*>(&Pl[wid][l15][kc * 32 + lk]);
#pragma unroll
          for (int n = 0; n < 4; ++n) {
            bf16x8 vf = *reinterpret_cast<const bf16x8*>(
                vb_ + (n * 16 + l15) * 128 + ((kc * 64 + g * 16) ^ swz));
            oacc[n] = __builtin_amdgcn_mfma_f32_16x16x32_bf16(vf, pb, oacc[n], 0, 0, 0);
          }
        }
      }
      __syncthreads();   // drains own vmcnt (next tile staged) + WAR protection
    }

    // epilogue: lane owns query qbase+l15; d = n*16 + g*4 + r
    float inv = 1.f / l_run;
    bf16* cp = ctx + ((size_t)b * N_ + qbase + l15) * D_ + h * HD_;
#pragma unroll
    for (int n = 0; n < 4; ++n) {
      bf16x4 o;
#pragma unroll
      for (int r = 0; r < 4; ++r) o[r] = (bf16)(oacc[n][r] * inv);
      *reinterpret_cast<bf16x4*>(cp + n * 16 + g * 4) = o;
    }
  }
}

// ---------------- launcher ----------------------------------------------------
extern "C" void kernel_launch(void* const* d_in, const int* in_sizes, int n_in,
                              void* d_out, int out_size, void* d_ws, size_t ws_size,
                              hipStream_t stream)
{
  const float* x  = (const float*)d_in[0];
  const float* Wq = (const float*)d_in[1];
  const float* Wk = (const float*)d_in[2];
  const float* Wv = (const float*)d_in[3];
  const float* Wo = (const float*)d_in[4];
  const float* bo = (const float*)d_in[5];
  float* out = (float*)d_out;

  const size_t SZ_BHND = (size_t)B_ * H_ * N_ * HD_ * sizeof(bf16); // 16 MiB
  const size_t SZ_W    = (size_t)D_ * D_ * sizeof(bf16);            // 2 MiB
  char* ws = (char*)d_ws;
  bf16* xbf  = (bf16*)(ws);                    // reused as ctx after QKV gemm
  bf16* ctx  = (bf16*)(ws);
  bf16* qb   = (bf16*)(ws + SZ_BHND);
  bf16* kbf  = (bf16*)(ws + 2 * SZ_BHND);
  bf16* vtb  = (bf16*)(ws + 3 * SZ_BHND);
  bf16* wqkv = (bf16*)(ws + 4 * SZ_BHND);      // [3072][1024]
  bf16* wob  = (bf16*)(ws + 4 * SZ_BHND + 3 * SZ_W);
  if (ws_size < 4 * SZ_BHND + 4 * SZ_W) return;

  const int NX = B_ * N_ * D_;      // 8M
  cast_k<<<NX / (256 * 8), 256, 0, stream>>>(x, xbf, NX);
  cast_k<<<(D_ * D_) / (256 * 8), 256, 0, stream>>>(Wo, wob, D_ * D_);

  transpose3_k<<<dim3(32, 32, 3), dim3(32, 32), 0, stream>>>(Wq, Wk, Wv, wqkv);

  const int M = B_ * N_;  // 8192
  gemm_qkv<<<dim3(M / 128, 3 * D_ / 128), 256, 0, stream>>>(xbf, wqkv, qb, kbf, vtb);

  attn_k<<<512, 512, 0, stream>>>(qb, kbf, vtb, ctx);

  gemm_out<<<dim3(M / 128, D_ / 128), 256, 0, stream>>>(ctx, wob, out, bo);
}

// Round 7
// 197.619 us; speedup vs baseline: 2.1566x; 1.0089x over previous
//
#include <hip/hip_runtime.h>
#include <hip/hip_bf16.h>

typedef __bf16 bf16;
typedef __bf16 bf16x4 __attribute__((ext_vector_type(4)));
typedef __bf16 bf16x8 __attribute__((ext_vector_type(8)));
typedef float  f32x4  __attribute__((ext_vector_type(4)));

#define B_  4
#define N_  2048
#define D_  1024
#define H_  16
#define HD_ 64

// 0.125 (1/sqrt(64)) * log2(e): folded into Wq during transpose
#define QSCALE 0.1803368801111204f

__device__ __forceinline__ bf16x8 ld8(const bf16* p) {
  return *reinterpret_cast<const bf16x8*>(p);
}
__device__ __forceinline__ float max3f(float a, float b, float c) {
  return fmaxf(fmaxf(a, b), c);   // clang fuses to v_max3_f32
}

// async global->LDS, 16B per lane; lds base must be wave-uniform
__device__ __forceinline__ void gload16(const bf16* g, bf16* l) {
  __builtin_amdgcn_global_load_lds(
      (const __attribute__((address_space(1))) void*)g,
      (__attribute__((address_space(3))) void*)l, 16, 0, 0);
}

// ---------------- f32 -> bf16 cast (8 elems/thread) ----------------------------
__global__ __launch_bounds__(256) void cast_k(const float* __restrict__ in,
                                              bf16* __restrict__ out, int n) {
  int i = (blockIdx.x * 256 + threadIdx.x) * 8;
  if (i >= n) return;
  float4 a = *reinterpret_cast<const float4*>(in + i);
  float4 b = *reinterpret_cast<const float4*>(in + i + 4);
  bf16x8 o;
  o[0] = (bf16)a.x; o[1] = (bf16)a.y; o[2] = (bf16)a.z; o[3] = (bf16)a.w;
  o[4] = (bf16)b.x; o[5] = (bf16)b.y; o[6] = (bf16)b.z; o[7] = (bf16)b.w;
  *reinterpret_cast<bf16x8*>(out + i) = o;
}

// ---- fused transpose-cast of Wq/Wk/Wv (z selects): out[z][c][r] = s*in[z][r][c]
__global__ __launch_bounds__(1024)
void transpose3_k(const float* __restrict__ w0, const float* __restrict__ w1,
                  const float* __restrict__ w2, bf16* __restrict__ out) {
  __shared__ float t[32][33];
  const int z = blockIdx.z;
  const float* in = (z == 0) ? w0 : (z == 1) ? w1 : w2;
  const float scale = (z == 0) ? QSCALE : 1.0f;
  bf16* o = out + (size_t)z * D_ * D_;
  int c = blockIdx.x * 32 + threadIdx.x;
  int r = blockIdx.y * 32 + threadIdx.y;
  t[threadIdx.y][threadIdx.x] = in[r * D_ + c];
  __syncthreads();
  int oc = blockIdx.y * 32 + threadIdx.x;
  int orr = blockIdx.x * 32 + threadIdx.y;
  o[orr * D_ + oc] = (bf16)(scale * t[threadIdx.x][threadIdx.y]);
}

// ---- shared GEMM core: stage 128x32 A/B tiles via global_load_lds, 16 MFMA ----
#define GEMM_CORE(A_, Bt_, K_)                                                   \
  f32x4 acc[4][4] = {};                                                          \
  for (int kk = 0; kk < (K_); kk += 32) {                                        \
    _Pragma("unroll")                                                            \
    for (int j = 0; j < 2; ++j) {                                                \
      gload16(&(A_)[(size_t)(brow + wid * 32 + j * 16 + (lane >> 2)) * (K_) +    \
                    kk + (lane & 3) * 8],                                        \
              &As[(wid * 32 + j * 16) * 32]);                                    \
      gload16(&(Bt_)[(size_t)(bcol + wid * 32 + j * 16 + (lane >> 2)) * (K_) +   \
                     kk + (lane & 3) * 8],                                       \
              &Bs[(wid * 32 + j * 16) * 32]);                                    \
    }                                                                            \
    __syncthreads();                                                             \
    bf16x8 af[4], bfr[4];                                                        \
    _Pragma("unroll")                                                            \
    for (int m = 0; m < 4; ++m)                                                  \
      af[m] = *reinterpret_cast<const bf16x8*>(&As[(wr + m * 16 + l15) * 32 + lk]); \
    _Pragma("unroll")                                                            \
    for (int n = 0; n < 4; ++n)                                                  \
      bfr[n] = *reinterpret_cast<const bf16x8*>(&Bs[(wc + n * 16 + l15) * 32 + lk]); \
    _Pragma("unroll")                                                            \
    for (int m = 0; m < 4; ++m)                                                  \
      _Pragma("unroll")                                                          \
      for (int n = 0; n < 4; ++n)                                                \
        acc[m][n] = __builtin_amdgcn_mfma_f32_16x16x32_bf16(af[m], bfr[n],       \
                                                            acc[m][n], 0, 0, 0); \
    __syncthreads();                                                             \
  }

// ---------------- fused QKV GEMM: [8192,1024] x [3072,1024]^T ------------------
__global__ __launch_bounds__(256)
void gemm_qkv(const bf16* __restrict__ A, const bf16* __restrict__ Bt,
              bf16* __restrict__ qb, bf16* __restrict__ kb, bf16* __restrict__ vtb)
{
  __shared__ bf16 As[128 * 32];
  __shared__ bf16 Bs[128 * 32];
  const int tid  = threadIdx.x;
  const int lane = tid & 63;
  const int wid  = tid >> 6;
  const int brow = blockIdx.x * 128;
  const int bcol = blockIdx.y * 128;
  const int wr   = (wid >> 1) * 64;
  const int wc   = (wid & 1) * 64;
  const int l15  = lane & 15;
  const int lk   = (lane >> 4) * 8;

  GEMM_CORE(A, Bt, D_)

  const int which = bcol >> 10;   // 0:Q 1:K 2:V (block-uniform)
  bf16* outp = (which == 0) ? qb : (which == 1) ? kb : vtb;
  const int r0 = (lane >> 4) * 4;
#pragma unroll
  for (int m = 0; m < 4; ++m)
#pragma unroll
    for (int n = 0; n < 4; ++n)
#pragma unroll
      for (int r = 0; r < 4; ++r) {
        int grow = brow + wr + m * 16 + r0 + r;
        int gcol = (bcol & 1023) + wc + n * 16 + l15;
        int b = grow >> 11, nn = grow & (N_ - 1);
        int h = gcol >> 6, hd = gcol & 63;
        float v = acc[m][n][r];
        if (which == 2)
          outp[((size_t)((b * H_ + h) * HD_ + hd)) * N_ + nn] = (bf16)v;
        else
          outp[((((size_t)(b * H_ + h)) * N_ + nn) << 6) + hd] = (bf16)v;
      }
}

// ---------------- output GEMM: out[M,D] = ctx[M,D] x Wo[D,D]^T + bo ------------
__global__ __launch_bounds__(256)
void gemm_out(const bf16* __restrict__ A, const bf16* __restrict__ Bt,
              float* __restrict__ C, const float* __restrict__ bias)
{
  __shared__ bf16 As[128 * 32];
  __shared__ bf16 Bs[128 * 32];
  const int tid  = threadIdx.x;
  const int lane = tid & 63;
  const int wid  = tid >> 6;
  const int brow = blockIdx.x * 128;
  const int bcol = blockIdx.y * 128;
  const int wr   = (wid >> 1) * 64;
  const int wc   = (wid & 1) * 64;
  const int l15  = lane & 15;
  const int lk   = (lane >> 4) * 8;

  GEMM_CORE(A, Bt, D_)

  const int r0 = (lane >> 4) * 4;
#pragma unroll
  for (int m = 0; m < 4; ++m)
#pragma unroll
    for (int n = 0; n < 4; ++n)
#pragma unroll
      for (int r = 0; r < 4; ++r) {
        int grow = brow + wr + m * 16 + r0 + r;
        int gcol = bcol + wc + n * 16 + l15;
        C[(size_t)grow * D_ + gcol] = acc[m][n][r] + bias[gcol];
      }
}

// ---------------- fused causal flash attention: 8-wave shared-KV blocks --------
// 512 blocks x 512 thr. Block = bh + complementary q-chunk pair {c, 15-c}.
// K/V: triple-buffered LDS, depth-2 prefetch, counted vmcnt(2) + raw s_barrier.
// l obtained from a ones-row PV MFMA column (no in-loop sum reduction).
__global__ __launch_bounds__(512, 4)
void attn_k(const bf16* __restrict__ q, const bf16* __restrict__ k,
            const bf16* __restrict__ vt, bf16* __restrict__ ctx)
{
  __shared__ bf16 Ks[3 * 64 * 64];
  __shared__ bf16 Vs[3 * 64 * 64];
  __shared__ bf16 Pl[8][16][72];
  const int tid  = threadIdx.x;
  const int lane = tid & 63;
  const int wid  = tid >> 6;
  const int bid  = blockIdx.x;
  const int bh   = bid & 63;
  const int cpr  = bid >> 6;          // 0..7
  const int l15  = lane & 15;
  const int g    = lane >> 4;
  const int lk   = g * 8;
  const int swz  = (l15 & 7) << 4;    // read-side XOR swizzle (bytes)

  const bf16* kp = k  + (size_t)bh * N_ * HD_;
  const bf16* vp = vt + (size_t)bh * HD_ * N_;
  const int b = bh >> 4, h = bh & 15;

  // staging: lane -> 1 row of K (key) / V (d); dest linear, source pre-swizzled
  const int srow  = wid * 8 + (lane >> 3);             // 0..63
  const int scoff = ((lane & 7) ^ (srow & 7)) * 8;     // elems
  const int sdoff = wid * 8 * 64;                      // wave's LDS region

  bf16x8 ones8;
#pragma unroll
  for (int i = 0; i < 8; ++i) ones8[i] = (bf16)1.0f;

#pragma unroll
  for (int p = 0; p < 2; ++p) {
    const int qb0   = (p == 0 ? cpr : 15 - cpr) * 128;
    const int qbase = qb0 + wid * 16;
    const int nt    = qb0 / 64 + 2;          // KV tiles this phase (>= 2)
    const int tm    = qbase >> 6;            // diagonal tile index for this wave

    const bf16* qp = q + ((size_t)bh * N_ + qbase) * HD_;
    bf16x8 aq[2];
#pragma unroll
    for (int c2 = 0; c2 < 2; ++c2)
      aq[c2] = ld8(qp + (size_t)l15 * HD_ + c2 * 32 + lk);

    float m_run = -1e30f;
    f32x4 oacc[5] = {};     // [0..3]: O^T d-tiles; [4]: l (ones-row PV)

    // prologue: stage tiles 0 and 1
    gload16(kp + (size_t)srow * HD_ + scoff, Ks + sdoff);
    gload16(vp + (size_t)srow * N_ + scoff, Vs + sdoff);
    gload16(kp + (size_t)(64 + srow) * HD_ + scoff, Ks + 4096 + sdoff);
    gload16(vp + (size_t)srow * N_ + 64 + scoff, Vs + 4096 + sdoff);
    asm volatile("s_waitcnt vmcnt(2)" ::: "memory");
    __builtin_amdgcn_s_barrier();
    __builtin_amdgcn_sched_barrier(0);

    int cur = 0, nxt = 2;
    for (int t = 0; t < nt; ++t) {
      if (t + 2 < nt) {   // stage tile t+2 into buf nxt
        const int kb = (t + 2) * 64;
        gload16(kp + (size_t)(kb + srow) * HD_ + scoff, Ks + nxt * 4096 + sdoff);
        gload16(vp + (size_t)srow * N_ + kb + scoff, Vs + nxt * 4096 + sdoff);
      }
      if (t <= tm) {      // wave-uniform: tiles with unmasked keys only
        const char* kb_ = (const char*)Ks + cur * 8192;
        const char* vb_ = (const char*)Vs + cur * 8192;

        // QK^T (swapped): S^T[key][q], A = K rows, B = Q cols
        f32x4 s[4] = {};
#pragma unroll
        for (int tt = 0; tt < 4; ++tt) {
          bf16x8 bk0 = *reinterpret_cast<const bf16x8*>(
              kb_ + (tt * 16 + l15) * 128 + ((g * 16) ^ swz));
          bf16x8 bk1 = *reinterpret_cast<const bf16x8*>(
              kb_ + (tt * 16 + l15) * 128 + ((64 + g * 16) ^ swz));
          s[tt] = __builtin_amdgcn_mfma_f32_16x16x32_bf16(bk0, aq[0], s[tt], 0, 0, 0);
          s[tt] = __builtin_amdgcn_mfma_f32_16x16x32_bf16(bk1, aq[1], s[tt], 0, 0, 0);
        }

        if (t == tm) {    // causal mask on the diagonal tile
          const int qr = qbase + l15;
#pragma unroll
          for (int tt = 0; tt < 4; ++tt)
#pragma unroll
            for (int r = 0; r < 4; ++r) {
              int kq = t * 64 + tt * 16 + g * 4 + r;
              if (kq > qr) s[tt][r] = -1e30f;
            }
        }

        // tile max via max3 chain + 2 shfl
        float pm = max3f(s[0][0], s[0][1], s[0][2]);
        pm = max3f(pm, s[0][3], s[1][0]);
        pm = max3f(pm, s[1][1], s[1][2]);
        pm = max3f(pm, s[1][3], s[2][0]);
        pm = max3f(pm, s[2][1], s[2][2]);
        pm = max3f(pm, s[2][3], s[3][0]);
        pm = max3f(pm, s[3][1], s[3][2]);
        pm = fmaxf(pm, s[3][3]);
        pm = fmaxf(pm, __shfl_xor(pm, 16));
        pm = fmaxf(pm, __shfl_xor(pm, 32));
        if (!__all(pm <= m_run + 8.f)) {   // defer-max (log2 domain)
          float mn = fmaxf(m_run, pm);
          float al = exp2f(m_run - mn);
          m_run = mn;
#pragma unroll
          for (int n = 0; n < 5; ++n)      // includes l column
#pragma unroll
            for (int r = 0; r < 4; ++r) oacc[n][r] *= al;
        }
#pragma unroll
        for (int tt = 0; tt < 4; ++tt)
#pragma unroll
          for (int r = 0; r < 4; ++r) s[tt][r] = exp2f(s[tt][r] - m_run);

        // P[q][key] -> per-wave LDS (C-layout -> B-layout transpose)
#pragma unroll
        for (int tt = 0; tt < 4; ++tt) {
          bf16x4 pk;
#pragma unroll
          for (int r = 0; r < 4; ++r) pk[r] = (bf16)s[tt][r];
          *reinterpret_cast<bf16x4*>(&Pl[wid][l15][tt * 16 + g * 4]) = pk;
        }

        // PV: O^T += V^T(LDS) * P; l += ones * P
#pragma unroll
        for (int kc = 0; kc < 2; ++kc) {
          bf16x8 pb = *reinterpret_cast<const bf16x8*>(&Pl[wid][l15][kc * 32 + lk]);
#pragma unroll
          for (int n = 0; n < 4; ++n) {
            bf16x8 vf = *reinterpret_cast<const bf16x8*>(
                vb_ + (n * 16 + l15) * 128 + ((kc * 64 + g * 16) ^ swz));
            oacc[n] = __builtin_amdgcn_mfma_f32_16x16x32_bf16(vf, pb, oacc[n], 0, 0, 0);
          }
          oacc[4] = __builtin_amdgcn_mfma_f32_16x16x32_bf16(ones8, pb, oacc[4], 0, 0, 0);
        }
      }
      // counted drain: tile t+1 must be resident; t+2 may stay in flight
      if (t + 2 < nt) {
        asm volatile("s_waitcnt vmcnt(2)" ::: "memory");
      } else if (t + 1 < nt) {
        asm volatile("s_waitcnt vmcnt(0)" ::: "memory");
      }
      __builtin_amdgcn_s_barrier();
      __builtin_amdgcn_sched_barrier(0);
      cur = (cur == 2) ? 0 : cur + 1;
      nxt = (nxt == 2) ? 0 : nxt + 1;
    }

    // epilogue: lane owns query qbase+l15; d = n*16 + g*4 + r; l = oacc[4][*]
    float inv = 1.f / oacc[4][0];
    bf16* cp = ctx + ((size_t)b * N_ + qbase + l15) * D_ + h * HD_;
#pragma unroll
    for (int n = 0; n < 4; ++n) {
      bf16x4 o;
#pragma unroll
      for (int r = 0; r < 4; ++r) o[r] = (bf16)(oacc[n][r] * inv);
      *reinterpret_cast<bf16x4*>(cp + n * 16 + g * 4) = o;
    }
  }
}

// ---------------- launcher ----------------------------------------------------
extern "C" void kernel_launch(void* const* d_in, const int* in_sizes, int n_in,
                              void* d_out, int out_size, void* d_ws, size_t ws_size,
                              hipStream_t stream)
{
  const float* x  = (const float*)d_in[0];
  const float* Wq = (const float*)d_in[1];
  const float* Wk = (const float*)d_in[2];
  const float* Wv = (const float*)d_in[3];
  const float* Wo = (const float*)d_in[4];
  const float* bo = (const float*)d_in[5];
  float* out = (float*)d_out;

  const size_t SZ_BHND = (size_t)B_ * H_ * N_ * HD_ * sizeof(bf16); // 16 MiB
  const size_t SZ_W    = (size_t)D_ * D_ * sizeof(bf16);            // 2 MiB
  char* ws = (char*)d_ws;
  bf16* xbf  = (bf16*)(ws);                    // reused as ctx after QKV gemm
  bf16* ctx  = (bf16*)(ws);
  bf16* qb   = (bf16*)(ws + SZ_BHND);
  bf16* kbf  = (bf16*)(ws + 2 * SZ_BHND);
  bf16* vtb  = (bf16*)(ws + 3 * SZ_BHND);
  bf16* wqkv = (bf16*)(ws + 4 * SZ_BHND);      // [3072][1024]
  bf16* wob  = (bf16*)(ws + 4 * SZ_BHND + 3 * SZ_W);
  if (ws_size < 4 * SZ_BHND + 4 * SZ_W) return;

  const int NX = B_ * N_ * D_;      // 8M
  cast_k<<<NX / (256 * 8), 256, 0, stream>>>(x, xbf, NX);
  cast_k<<<(D_ * D_) / (256 * 8), 256, 0, stream>>>(Wo, wob, D_ * D_);

  transpose3_k<<<dim3(32, 32, 3), dim3(32, 32), 0, stream>>>(Wq, Wk, Wv, wqkv);

  const int M = B_ * N_;  // 8192
  gemm_qkv<<<dim3(M / 128, 3 * D_ / 128), 256, 0, stream>>>(xbf, wqkv, qb, kbf, vtb);

  attn_k<<<512, 512, 0, stream>>>(qb, kbf, vtb, ctx);

  gemm_out<<<dim3(M / 128, D_ / 128), 256, 0, stream>>>(ctx, wob, out, bo);
}

// Round 9
// 195.073 us; speedup vs baseline: 2.1848x; 1.0130x over previous
//
#include <hip/hip_runtime.h>
#include <hip/hip_bf16.h>

typedef __bf16 bf16;
typedef __bf16 bf16x4 __attribute__((ext_vector_type(4)));
typedef __bf16 bf16x8 __attribute__((ext_vector_type(8)));
typedef float  f32x4  __attribute__((ext_vector_type(4)));

#define B_  4
#define N_  2048
#define D_  1024
#define H_  16
#define HD_ 64

// 0.125 (1/sqrt(64)) * log2(e): folded into Wq during transpose
#define QSCALE 0.1803368801111204f

__device__ __forceinline__ bf16x8 ld8(const bf16* p) {
  return *reinterpret_cast<const bf16x8*>(p);
}
__device__ __forceinline__ float max3f(float a, float b, float c) {
  return fmaxf(fmaxf(a, b), c);   // clang fuses to v_max3_f32
}

// async global->LDS, 16B per lane; lds base must be wave-uniform
__device__ __forceinline__ void gload16(const bf16* g, bf16* l) {
  __builtin_amdgcn_global_load_lds(
      (const __attribute__((address_space(1))) void*)g,
      (__attribute__((address_space(3))) void*)l, 16, 0, 0);
}

// ---------------- f32 -> bf16 cast (8 elems/thread) ----------------------------
__global__ __launch_bounds__(256) void cast_k(const float* __restrict__ in,
                                              bf16* __restrict__ out, int n) {
  int i = (blockIdx.x * 256 + threadIdx.x) * 8;
  if (i >= n) return;
  float4 a = *reinterpret_cast<const float4*>(in + i);
  float4 b = *reinterpret_cast<const float4*>(in + i + 4);
  bf16x8 o;
  o[0] = (bf16)a.x; o[1] = (bf16)a.y; o[2] = (bf16)a.z; o[3] = (bf16)a.w;
  o[4] = (bf16)b.x; o[5] = (bf16)b.y; o[6] = (bf16)b.z; o[7] = (bf16)b.w;
  *reinterpret_cast<bf16x8*>(out + i) = o;
}

// ---- fused transpose-cast of Wq/Wk/Wv (z selects): out[z][c][r] = s*in[z][r][c]
__global__ __launch_bounds__(1024)
void transpose3_k(const float* __restrict__ w0, const float* __restrict__ w1,
                  const float* __restrict__ w2, bf16* __restrict__ out) {
  __shared__ float t[32][33];
  const int z = blockIdx.z;
  const float* in = (z == 0) ? w0 : (z == 1) ? w1 : w2;
  const float scale = (z == 0) ? QSCALE : 1.0f;
  bf16* o = out + (size_t)z * D_ * D_;
  int c = blockIdx.x * 32 + threadIdx.x;
  int r = blockIdx.y * 32 + threadIdx.y;
  t[threadIdx.y][threadIdx.x] = in[r * D_ + c];
  __syncthreads();
  int oc = blockIdx.y * 32 + threadIdx.x;
  int orr = blockIdx.x * 32 + threadIdx.y;
  o[orr * D_ + oc] = (bf16)(scale * t[threadIdx.x][threadIdx.y]);
}

// ---- shared GEMM core: stage 128x32 A/B tiles via global_load_lds, 16 MFMA ----
#define GEMM_CORE(A_, Bt_, K_)                                                   \
  f32x4 acc[4][4] = {};                                                          \
  for (int kk = 0; kk < (K_); kk += 32) {                                        \
    _Pragma("unroll")                                                            \
    for (int j = 0; j < 2; ++j) {                                                \
      gload16(&(A_)[(size_t)(brow + wid * 32 + j * 16 + (lane >> 2)) * (K_) +    \
                    kk + (lane & 3) * 8],                                        \
              &As[(wid * 32 + j * 16) * 32]);                                    \
      gload16(&(Bt_)[(size_t)(bcol + wid * 32 + j * 16 + (lane >> 2)) * (K_) +   \
                     kk + (lane & 3) * 8],                                       \
              &Bs[(wid * 32 + j * 16) * 32]);                                    \
    }                                                                            \
    __syncthreads();                                                             \
    bf16x8 af[4], bfr[4];                                                        \
    _Pragma("unroll")                                                            \
    for (int m = 0; m < 4; ++m)                                                  \
      af[m] = *reinterpret_cast<const bf16x8*>(&As[(wr + m * 16 + l15) * 32 + lk]); \
    _Pragma("unroll")                                                            \
    for (int n = 0; n < 4; ++n)                                                  \
      bfr[n] = *reinterpret_cast<const bf16x8*>(&Bs[(wc + n * 16 + l15) * 32 + lk]); \
    _Pragma("unroll")                                                            \
    for (int m = 0; m < 4; ++m)                                                  \
      _Pragma("unroll")                                                          \
      for (int n = 0; n < 4; ++n)                                                \
        acc[m][n] = __builtin_amdgcn_mfma_f32_16x16x32_bf16(af[m], bfr[n],       \
                                                            acc[m][n], 0, 0, 0); \
    __syncthreads();                                                             \
  }

// ---------------- fused QKV GEMM: [8192,1024] x [3072,1024]^T ------------------
// 1D grid 1536; XCD macro-tiling: xcd = wg&7 owns C rows 8*xcd..8*xcd+7 (all 24
// col-blocks) -> per-XCD A working set 2 MB stays L2-resident.
__global__ __launch_bounds__(256)
void gemm_qkv(const bf16* __restrict__ A, const bf16* __restrict__ Bt,
              bf16* __restrict__ qb, bf16* __restrict__ kb, bf16* __restrict__ vtb)
{
  __shared__ bf16 As[128 * 32];
  __shared__ bf16 Bs[128 * 32];
  const int tid  = threadIdx.x;
  const int lane = tid & 63;
  const int wid  = tid >> 6;
  const int wg   = blockIdx.x;
  const int xcd  = wg & 7;
  const int idx  = wg >> 3;                 // 0..191
  const int brow = ((xcd << 3) + (idx & 7)) * 128;
  const int bcol = (idx >> 3) * 128;        // 0..23 blocks
  const int wr   = (wid >> 1) * 64;
  const int wc   = (wid & 1) * 64;
  const int l15  = lane & 15;
  const int lk   = (lane >> 4) * 8;

  GEMM_CORE(A, Bt, D_)

  const int which = bcol >> 10;   // 0:Q 1:K 2:V (block-uniform)
  bf16* outp = (which == 0) ? qb : (which == 1) ? kb : vtb;
  const int r0 = (lane >> 4) * 4;
#pragma unroll
  for (int m = 0; m < 4; ++m)
#pragma unroll
    for (int n = 0; n < 4; ++n)
#pragma unroll
      for (int r = 0; r < 4; ++r) {
        int grow = brow + wr + m * 16 + r0 + r;
        int gcol = (bcol & 1023) + wc + n * 16 + l15;
        int b = grow >> 11, nn = grow & (N_ - 1);
        int h = gcol >> 6, hd = gcol & 63;
        float v = acc[m][n][r];
        if (which == 2)
          outp[((size_t)((b * H_ + h) * HD_ + hd)) * N_ + nn] = (bf16)v;
        else
          outp[((((size_t)(b * H_ + h)) * N_ + nn) << 6) + hd] = (bf16)v;
      }
}

// ---------------- output GEMM: out[M,D] = ctx[M,D] x Wo[D,D]^T + bo ------------
// 1D grid 512; same XCD macro-tiling (A 2MB + B 2MB per XCD -> L2-resident).
__global__ __launch_bounds__(256)
void gemm_out(const bf16* __restrict__ A, const bf16* __restrict__ Bt,
              float* __restrict__ C, const float* __restrict__ bias)
{
  __shared__ bf16 As[128 * 32];
  __shared__ bf16 Bs[128 * 32];
  const int tid  = threadIdx.x;
  const int lane = tid & 63;
  const int wid  = tid >> 6;
  const int wg   = blockIdx.x;
  const int xcd  = wg & 7;
  const int idx  = wg >> 3;                 // 0..63
  const int brow = ((xcd << 3) + (idx & 7)) * 128;
  const int bcol = (idx >> 3) * 128;        // 0..7 blocks
  const int wr   = (wid >> 1) * 64;
  const int wc   = (wid & 1) * 64;
  const int l15  = lane & 15;
  const int lk   = (lane >> 4) * 8;

  GEMM_CORE(A, Bt, D_)

  const int r0 = (lane >> 4) * 4;
#pragma unroll
  for (int m = 0; m < 4; ++m)
#pragma unroll
    for (int n = 0; n < 4; ++n)
#pragma unroll
      for (int r = 0; r < 4; ++r) {
        int grow = brow + wr + m * 16 + r0 + r;
        int gcol = bcol + wc + n * 16 + l15;
        C[(size_t)grow * D_ + gcol] = acc[m][n][r] + bias[gcol];
      }
}

// ---------------- fused causal flash attention: 8-wave shared-KV blocks --------
// 512 blocks x 512 thr, 50 KB LDS -> 3 blocks/CU. Double-buffered K/V via
// global_load_lds (pre-swizzled source, swizzled reads). Defer-max softmax
// (THR=8, log2 domain); l from a ones-row PV MFMA column.
__global__ __launch_bounds__(512, 6)
void attn_k(const bf16* __restrict__ q, const bf16* __restrict__ k,
            const bf16* __restrict__ vt, bf16* __restrict__ ctx)
{
  __shared__ bf16 Ks[2][64 * 64];
  __shared__ bf16 Vs[2][64 * 64];
  __shared__ bf16 Pl[8][16][72];      // 16 q x 64 keys + 8 pad (DO NOT SHRINK)
  const int tid  = threadIdx.x;
  const int lane = tid & 63;
  const int wid  = tid >> 6;
  const int bid  = blockIdx.x;
  const int bh   = bid & 63;
  const int cpr  = bid >> 6;          // 0..7
  const int l15  = lane & 15;
  const int g    = lane >> 4;
  const int lk   = g * 8;
  const int swz  = (l15 & 7) << 4;    // read-side XOR swizzle (bytes)

  const bf16* kp = k  + (size_t)bh * N_ * HD_;
  const bf16* vp = vt + (size_t)bh * HD_ * N_;
  const int b = bh >> 4, h = bh & 15;

  // staging: lane -> 1 row of K (key) / V (d); dest linear, source pre-swizzled
  const int srow  = wid * 8 + (lane >> 3);             // 0..63
  const int scoff = ((lane & 7) ^ (srow & 7)) * 8;     // elems
  const int sdoff = wid * 8 * 64;                      // wave's LDS region

  bf16x8 ones8;
#pragma unroll
  for (int i = 0; i < 8; ++i) ones8[i] = (bf16)1.0f;

#pragma unroll
  for (int p = 0; p < 2; ++p) {
    const int qb0   = (p == 0 ? cpr : 15 - cpr) * 128;
    const int qbase = qb0 + wid * 16;
    const int nt    = qb0 / 64 + 2;          // KV tiles this phase (>= 2)
    const int tm    = qbase >> 6;            // diagonal tile index for this wave

    const bf16* qp = q + ((size_t)bh * N_ + qbase) * HD_;
    bf16x8 aq[2];
#pragma unroll
    for (int c2 = 0; c2 < 2; ++c2)
      aq[c2] = ld8(qp + (size_t)l15 * HD_ + c2 * 32 + lk);

    float m_run = -1e30f;
    f32x4 oacc[5] = {};     // [0..3]: O^T d-tiles; [4]: l (ones-row PV)

    // prologue: stage tile 0 into buf 0
    gload16(kp + (size_t)srow * HD_ + scoff, &Ks[0][sdoff]);
    gload16(vp + (size_t)srow * N_ + scoff, &Vs[0][sdoff]);
    __syncthreads();

    for (int t = 0; t < nt; ++t) {
      const int cur = t & 1;
      if (t + 1 < nt) {   // issue next-tile stage; latency hides under compute
        const int kb = (t + 1) * 64;
        gload16(kp + (size_t)(kb + srow) * HD_ + scoff, &Ks[cur ^ 1][sdoff]);
        gload16(vp + (size_t)srow * N_ + kb + scoff, &Vs[cur ^ 1][sdoff]);
      }
      if (t <= tm) {      // wave-uniform: tiles with unmasked keys only
        const char* kb_ = (const char*)&Ks[cur][0];
        const char* vb_ = (const char*)&Vs[cur][0];

        // QK^T (swapped): S^T[key][q], A = K rows, B = Q cols
        f32x4 s[4] = {};
#pragma unroll
        for (int tt = 0; tt < 4; ++tt) {
          bf16x8 bk0 = *reinterpret_cast<const bf16x8*>(
              kb_ + (tt * 16 + l15) * 128 + ((g * 16) ^ swz));
          bf16x8 bk1 = *reinterpret_cast<const bf16x8*>(
              kb_ + (tt * 16 + l15) * 128 + ((64 + g * 16) ^ swz));
          s[tt] = __builtin_amdgcn_mfma_f32_16x16x32_bf16(bk0, aq[0], s[tt], 0, 0, 0);
          s[tt] = __builtin_amdgcn_mfma_f32_16x16x32_bf16(bk1, aq[1], s[tt], 0, 0, 0);
        }

        if (t == tm) {    // causal mask on the diagonal tile
          const int qr = qbase + l15;
#pragma unroll
          for (int tt = 0; tt < 4; ++tt)
#pragma unroll
            for (int r = 0; r < 4; ++r) {
              int kq = t * 64 + tt * 16 + g * 4 + r;
              if (kq > qr) s[tt][r] = -1e30f;
            }
        }

        // tile max via max3 chain + 2 shfl
        float pm = max3f(s[0][0], s[0][1], s[0][2]);
        pm = max3f(pm, s[0][3], s[1][0]);
        pm = max3f(pm, s[1][1], s[1][2]);
        pm = max3f(pm, s[1][3], s[2][0]);
        pm = max3f(pm, s[2][1], s[2][2]);
        pm = max3f(pm, s[2][3], s[3][0]);
        pm = max3f(pm, s[3][1], s[3][2]);
        pm = fmaxf(pm, s[3][3]);
        pm = fmaxf(pm, __shfl_xor(pm, 16));
        pm = fmaxf(pm, __shfl_xor(pm, 32));
        if (!__all(pm <= m_run + 8.f)) {   // defer-max (log2 domain)
          float mn = fmaxf(m_run, pm);
          float al = exp2f(m_run - mn);
          m_run = mn;
#pragma unroll
          for (int n = 0; n < 5; ++n)      // includes l column
#pragma unroll
            for (int r = 0; r < 4; ++r) oacc[n][r] *= al;
        }
#pragma unroll
        for (int tt = 0; tt < 4; ++tt)
#pragma unroll
          for (int r = 0; r < 4; ++r) s[tt][r] = exp2f(s[tt][r] - m_run);

        // P[q][key] -> per-wave LDS (C-layout -> B-layout transpose)
#pragma unroll
        for (int tt = 0; tt < 4; ++tt) {
          bf16x4 pk;
#pragma unroll
          for (int r = 0; r < 4; ++r) pk[r] = (bf16)s[tt][r];
          *reinterpret_cast<bf16x4*>(&Pl[wid][l15][tt * 16 + g * 4]) = pk;
        }

        // PV: O^T += V^T(LDS) * P; l += ones * P
#pragma unroll
        for (int kc = 0; kc < 2; ++kc) {
          bf16x8 pb = *reinterpret_cast<const bf16x8*>(&Pl[wid][l15][kc * 32 + lk]);
#pragma unroll
          for (int n = 0; n < 4; ++n) {
            bf16x8 vf = *reinterpret_cast<const bf16x8*>(
                vb_ + (n * 16 + l15) * 128 + ((kc * 64 + g * 16) ^ swz));
            oacc[n] = __builtin_amdgcn_mfma_f32_16x16x32_bf16(vf, pb, oacc[n], 0, 0, 0);
          }
          oacc[4] = __builtin_amdgcn_mfma_f32_16x16x32_bf16(ones8, pb, oacc[4], 0, 0, 0);
        }
      }
      __syncthreads();   // drains own vmcnt (tile t+1 staged) + WAR protection
    }

    // epilogue: lane owns query qbase+l15; d = n*16 + g*4 + r; l = oacc[4][*]
    float inv = 1.f / oacc[4][0];
    bf16* cp = ctx + ((size_t)b * N_ + qbase + l15) * D_ + h * HD_;
#pragma unroll
    for (int n = 0; n < 4; ++n) {
      bf16x4 o;
#pragma unroll
      for (int r = 0; r < 4; ++r) o[r] = (bf16)(oacc[n][r] * inv);
      *reinterpret_cast<bf16x4*>(cp + n * 16 + g * 4) = o;
    }
  }
}

// ---------------- launcher ----------------------------------------------------
extern "C" void kernel_launch(void* const* d_in, const int* in_sizes, int n_in,
                              void* d_out, int out_size, void* d_ws, size_t ws_size,
                              hipStream_t stream)
{
  const float* x  = (const float*)d_in[0];
  const float* Wq = (const float*)d_in[1];
  const float* Wk = (const float*)d_in[2];
  const float* Wv = (const float*)d_in[3];
  const float* Wo = (const float*)d_in[4];
  const float* bo = (const float*)d_in[5];
  float* out = (float*)d_out;

  const size_t SZ_BHND = (size_t)B_ * H_ * N_ * HD_ * sizeof(bf16); // 16 MiB
  const size_t SZ_W    = (size_t)D_ * D_ * sizeof(bf16);            // 2 MiB
  char* ws = (char*)d_ws;
  bf16* xbf  = (bf16*)(ws);                    // reused as ctx after QKV gemm
  bf16* ctx  = (bf16*)(ws);
  bf16* qb   = (bf16*)(ws + SZ_BHND);
  bf16* kbf  = (bf16*)(ws + 2 * SZ_BHND);
  bf16* vtb  = (bf16*)(ws + 3 * SZ_BHND);
  bf16* wqkv = (bf16*)(ws + 4 * SZ_BHND);      // [3072][1024]
  bf16* wob  = (bf16*)(ws + 4 * SZ_BHND + 3 * SZ_W);
  if (ws_size < 4 * SZ_BHND + 4 * SZ_W) return;

  const int NX = B_ * N_ * D_;      // 8M
  cast_k<<<NX / (256 * 8), 256, 0, stream>>>(x, xbf, NX);
  cast_k<<<(D_ * D_) / (256 * 8), 256, 0, stream>>>(Wo, wob, D_ * D_);

  transpose3_k<<<dim3(32, 32, 3), dim3(32, 32), 0, stream>>>(Wq, Wk, Wv, wqkv);

  gemm_qkv<<<1536, 256, 0, stream>>>(xbf, wqkv, qb, kbf, vtb);

  attn_k<<<512, 512, 0, stream>>>(qb, kbf, vtb, ctx);

  gemm_out<<<512, 256, 0, stream>>>(ctx, wob, out, bo);
}